// Round 11
// baseline (148.239 us; speedup 1.0000x reference)
//
#include <hip/hip_runtime.h>
#include <hip/hip_bf16.h>
#include <math.h>

typedef short bf16x8 __attribute__((ext_vector_type(8)));
typedef float f32x4  __attribute__((ext_vector_type(4)));

constexpr int   H     = 256;
constexpr int   KNB   = 32;
constexpr int   GC    = 16;      // bin-grid cells per dim
constexpr float HINV  = 1.6f;    // GC / 10.0
constexpr float HCEL  = 0.625f;  // 10.0 / GC
constexpr int   SLOTS = 32;      // slots per cell (avg fill ~12.2; overflow spills)
constexpr int   OCAP  = 256;     // overflow list capacity
constexpr int   WCAP  = 192;     // per-wave candidate list capacity

__device__ __forceinline__ ushort f2bf(float x) {
    unsigned u = __float_as_uint(x);
    u += 0x7FFF + ((u >> 16) & 1);
    return (ushort)(u >> 16);
}

__device__ __forceinline__ float gelu_fast(float x) {
    float u = 0.7978845608028654f * (x + 0.044715f * x * x * x);
    float t = exp2f(-2.885390081777927f * u);
    return x / (1.0f + t);
}

__device__ __forceinline__ int cell_of(float x, float y, float z) {
    int cx = min(GC - 1, max(0, (int)(x * HINV)));
    int cy = min(GC - 1, max(0, (int)(y * HINV)));
    int cz = min(GC - 1, max(0, (int)(z * HINV)));
    return (cz * GC + cy) * GC + cx;
}

// ---- prep: W1t transpose (blocks 0..63); slotted scatter (rest) ----
__global__ __launch_bounds__(256)
void prep(const float* __restrict__ W1, const float* __restrict__ pos, int N,
          ushort* __restrict__ W1t, float4* __restrict__ pos4s,
          int* __restrict__ origidx, int* __restrict__ cellcnt,
          int* __restrict__ ovfidx, float4* __restrict__ ovfpos) {
    const int b = blockIdx.x;
    if (b < 64) {
        __shared__ float tile[32][33];
        const int ti = b >> 3, tj = b & 7;
        const int r  = threadIdx.x >> 5, c = threadIdx.x & 31;
#pragma unroll
        for (int rr = r; rr < 32; rr += 8)
            tile[rr][c] = W1[(ti * 32 + rr) * H + tj * 32 + c];
        __syncthreads();
#pragma unroll
        for (int rr = r; rr < 32; rr += 8) {
            int j = tj * 32 + rr;
            W1t[j * H + ti * 32 + c] = f2bf(tile[c][rr]);
        }
    } else {
        int i = (b - 64) * 256 + threadIdx.x;
        if (i < N) {
            float x = pos[3 * i], y = pos[3 * i + 1], z = pos[3 * i + 2];
            float4 P = make_float4(x, y, z, 0.f);
            int c = cell_of(x, y, z);
            int slot = atomicAdd(&cellcnt[c], 1);
            if (slot < SLOTS) {
                pos4s[c * SLOTS + slot] = P;
                origidx[c * SLOTS + slot] = i;
            } else {
                int o = atomicAdd(&cellcnt[4096], 1);
                if (o < OCAP) { ovfpos[o] = P; ovfidx[o] = i; }
            }
        }
    }
}

// ---- wave-synchronous exact kNN: one wave per supernode, ZERO barriers ----
__global__ __launch_bounds__(256)
void wave_select(const float* __restrict__ pos,
                 const float4* __restrict__ pos4s,
                 const int* __restrict__ origidx,
                 const int* __restrict__ cellcnt,
                 const int* __restrict__ ovfidx, const float4* __restrict__ ovfpos,
                 const int* __restrict__ supidx, int S,
                 float4* __restrict__ rfM)
{
    __shared__ float wd2b[4][WCAP];
    __shared__ int   widb[4][WCAP];

    const int lane = threadIdx.x & 63;
    const int w    = threadIdx.x >> 6;
    const int s    = blockIdx.x * 4 + w;
    if (s >= S) return;

    float* wd2 = wd2b[w];
    int*   wid = widb[w];

    const int sidx = supidx[s];
    const float sx = pos[3 * sidx], sy = pos[3 * sidx + 1], sz = pos[3 * sidx + 2];

    // ---- window: 5^3 cells around s, 2 per lane ----
    const int scx = min(GC - 1, max(0, (int)(sx * HINV)));
    const int scy = min(GC - 1, max(0, (int)(sy * HINV)));
    const int scz = min(GC - 1, max(0, (int)(sz * HINV)));

    float amax[2];
    int   pk[2];      // (cell<<7) | (p1<<6) | cnt
#pragma unroll
    for (int sl = 0; sl < 2; sl++) {
        int ci = lane + sl * 64;
        int X = scx - 2 + ci % 5;
        int Y = scy - 2 + (ci / 5) % 5;
        int Z = scz - 2 + ci / 25;
        bool val = (ci < 125) && X >= 0 && X < GC && Y >= 0 && Y < GC && Z >= 0 && Z < GC;
        int cell = val ? (Z * GC + Y) * GC + X : 0;
        int cn = val ? min(cellcnt[cell], SLOTS) : 0;
        float am = 1e30f;
        if (cn > 0) {
            float lx = X * HCEL, ly = Y * HCEL, lz = Z * HCEL;
            float mx = fmaxf(fabsf(sx - lx), fabsf(lx + HCEL - sx));
            float my = fmaxf(fabsf(sy - ly), fabsf(ly + HCEL - sy));
            float mz = fmaxf(fabsf(sz - lz), fabsf(lz + HCEL - sz));
            am = mx * mx + my * my + mz * mz;
        }
        amax[sl] = am;
        pk[sl] = (cell << 7) | cn;
    }

    // ---- tau_cells: weighted wave-rank (smallest amax with cum count >= 32) ----
    int S0 = 0, S1 = 0;
    for (int j = 0; j < 64; j++) {
        float a0 = __shfl(amax[0], j); int n0 = __shfl(pk[0], j) & 63;
        float a1 = __shfl(amax[1], j); int n1 = __shfl(pk[1], j) & 63;
        S0 += ((a0 < amax[0]) || (a0 == amax[0] && j < lane)) ? n0 : 0;
        S0 += ((a1 < amax[0]) || (a1 == amax[0] && j + 64 < lane)) ? n1 : 0;
        S1 += ((a0 < amax[1]) || (a0 == amax[1] && j < lane + 64)) ? n0 : 0;
        S1 += ((a1 < amax[1]) || (a1 == amax[1] && j + 64 < lane + 64)) ? n1 : 0;
    }
    float tc = 1e30f;
    int c0 = pk[0] & 63, c1 = pk[1] & 63;
    if (S0 < KNB && KNB <= S0 + c0) tc = amax[0];
    if (S1 < KNB && KNB <= S1 + c1) tc = fminf(tc, amax[1]);
#pragma unroll
    for (int off = 32; off; off >>= 1) tc = fminf(tc, __shfl_xor(tc, off));
    const float tau_cells = (tc < 1e29f) ? tc : 301.f;

    // p1 flags into pack bit 6
#pragma unroll
    for (int sl = 0; sl < 2; sl++)
        if ((pk[sl] & 63) > 0 && amax[sl] <= tau_cells) pk[sl] |= 64;

    // ---- phase 1: gather ALL points of p1 cells (>=32 guaranteed) ----
    int m = 0;
    for (int i = 0; i < 63; i++) {
        int cA = 2 * i, cB = 2 * i + 1;
        int pA = (cA & 64) ? __shfl(pk[1], cA & 63) : __shfl(pk[0], cA & 63);
        int pB = (cB & 64) ? __shfl(pk[1], cB & 63) : __shfl(pk[0], cB & 63);
        bool fA = (pA >> 6) & 1, fB = (pB >> 6) & 1;
        if (!fA && !fB) continue;
        int half = lane >> 5, sic = lane & 31;
        int p = half ? pB : pA;
        bool act = ((half ? fB : fA) != 0) && sic < (p & 63);
        float d2 = 0.f; int oi = 0;
        if (act) {
            int base = (p >> 7) * SLOTS + sic;
            float4 P = pos4s[base];
            float dx = sx - P.x, dy = sy - P.y, dz = sz - P.z;
            d2 = dx * dx + dy * dy + dz * dz;
            oi = origidx[base];
        }
        unsigned long long mk = __ballot(act);
        int off = __popcll(mk & ((1ull << lane) - 1ull));
        if (act && m + off < WCAP) { wd2[m + off] = d2; wid[m + off] = oi; }
        m = min(m + __popcll(mk), (long long)WCAP);
    }

    // ---- tau* = exact 32nd-smallest of phase-1 set (chunked shuffle-rank) ----
    auto ranked = [&](int mm, float* mv, int* mi, int* rk, int& myn) {
        myn = 0;
        for (int u = lane; u < mm; u += 64) {
            mv[myn] = wd2[u]; mi[myn] = wid[u]; rk[myn] = 0; myn++;
        }
        int nch = (mm + 63) >> 6;
        for (int c = 0; c < nch; c++) {
            int idx = c * 64 + lane;
            bool lv = idx < mm;
            float rv = lv ? wd2[idx] : 1e30f;
            int   ri = lv ? wid[idx] : 0x7fffffff;
            for (int j = 0; j < 64; j++) {
                float bv = __shfl(rv, j);
                int   bi = __shfl(ri, j);
#pragma unroll
                for (int k = 0; k < 3; k++)
                    if (k < myn) rk[k] += (bv < mv[k]) || (bv == mv[k] && bi < mi[k]);
            }
        }
    };

    float tstar;
    {
        float mv[3]; int mi[3]; int rk[3]; int myn;
        ranked(m, mv, mi, rk, myn);
        float ts = 1e30f;
#pragma unroll
        for (int k = 0; k < 3; k++)
            if (k < myn && rk[k] == KNB - 1) ts = mv[k];
#pragma unroll
        for (int off = 32; off; off >>= 1) ts = fminf(ts, __shfl_xor(ts, off));
        tstar = (ts < 1e29f) ? ts : tau_cells;
    }

    // ---- phase 2: fresh gather of ALL points with d2 <= tau* ----
    const float Rb = sqrtf(tstar) * 1.000001f + 1e-6f;
    const int bx0 = max(0, (int)floorf((sx - Rb) * HINV));
    const int bx1 = min(GC - 1, (int)floorf((sx + Rb) * HINV));
    const int by0 = max(0, (int)floorf((sy - Rb) * HINV));
    const int by1 = min(GC - 1, (int)floorf((sy + Rb) * HINV));
    const int bz0 = max(0, (int)floorf((sz - Rb) * HINV));
    const int bz1 = min(GC - 1, (int)floorf((sz + Rb) * HINV));
    const int nbx = bx1 - bx0 + 1, nby = by1 - by0 + 1, nbz = bz1 - bz0 + 1;
    const int ncb = nbx * nby * nbz;

    m = 0;
    for (int ib = 0; ib < ncb; ib += 2) {
        int ci = ib + (lane >> 5);
        bool cv = ci < ncb;
        int X = bx0 + ci % nbx, rem = ci / nbx;
        int Y = by0 + rem % nby, Z = bz0 + rem / nby;
        int cell = (Z * GC + Y) * GC + X;
        bool cellok = cv;
        if (cv) {
            float lx = X * HCEL, ly = Y * HCEL, lz = Z * HCEL;
            float ddx = fmaxf(fmaxf(lx - sx, sx - (lx + HCEL)), 0.f);
            float ddy = fmaxf(fmaxf(ly - sy, sy - (ly + HCEL)), 0.f);
            float ddz = fmaxf(fmaxf(lz - sz, sz - (lz + HCEL)), 0.f);
            cellok = (ddx * ddx + ddy * ddy + ddz * ddz) <= tstar + 1e-4f;
        }
        int cn = cellok ? min(cellcnt[cell], SLOTS) : 0;
        int sic = lane & 31;
        bool act = sic < cn;
        float d2 = 0.f; int oi = 0;
        if (act) {
            int base = cell * SLOTS + sic;
            float4 P = pos4s[base];
            float dx = sx - P.x, dy = sy - P.y, dz = sz - P.z;
            d2 = dx * dx + dy * dy + dz * dz;
            act = d2 <= tstar;
            if (act) oi = origidx[base];
        }
        unsigned long long mk = __ballot(act);
        int off = __popcll(mk & ((1ull << lane) - 1ull));
        if (act && m + off < WCAP) { wd2[m + off] = d2; wid[m + off] = oi; }
        m = min(m + __popcll(mk), (long long)WCAP);
    }
    // overflow spill list (expected empty)
    {
        int no = min(cellcnt[4096], OCAP);
        for (int j0 = 0; j0 < no; j0 += 64) {
            int j = j0 + lane;
            bool act = j < no;
            float d2 = 0.f; int oi = 0;
            if (act) {
                float4 P = ovfpos[j];
                float dx = sx - P.x, dy = sy - P.y, dz = sz - P.z;
                d2 = dx * dx + dy * dy + dz * dz;
                act = d2 <= tstar;
                if (act) oi = ovfidx[j];
            }
            unsigned long long mk = __ballot(act);
            int off = __popcll(mk & ((1ull << lane) - 1ull));
            if (act && m + off < WCAP) { wd2[m + off] = d2; wid[m + off] = oi; }
            m = min(m + __popcll(mk), (long long)WCAP);
        }
    }

    // ---- final exact rank -> top-32 -> rel features ----
    {
        float mv[3]; int mi[3]; int rk[3]; int myn;
        ranked(m, mv, mi, rk, myn);
#pragma unroll
        for (int k = 0; k < 3; k++) {
            if (k < myn && rk[k] < KNB) {
                int ni = mi[k];
                float px = pos[3 * ni], py = pos[3 * ni + 1], pz = pos[3 * ni + 2];
                float rx = sx - px, ry = sy - py, rz = sz - pz;
                float dd = sqrtf(rx * rx + ry * ry + rz * rz);
                rfM[s * KNB + rk[k]] = make_float4(rx, ry, rz, dd);
            }
        }
    }
}

// ---- K3: supE + sincos embed + MFMA GEMM1 + gelu/mean + W2 matvec ----
__global__ __launch_bounds__(512, 4)
void embed_gemm1(const float4* __restrict__ rfM,
                 const ushort* __restrict__ W1t, const float* __restrict__ b1,
                 const float* __restrict__ W2, const float* __restrict__ b2,
                 const float* __restrict__ pos, const int* __restrict__ supidx,
                 float* __restrict__ featsM)
{
    __shared__ __align__(16) char pool[16384];   // msg bf16[32][256] then p2 f32[8][256]
    ushort* msg = (ushort*)pool;
    float*  p2  = (float*)pool;
    __shared__ float rf[KNB][5];
    __shared__ float hb[H];

    const int s    = blockIdx.x;
    const int t    = threadIdx.x;
    const int lane = t & 63;
    const int w    = t >> 6;

    constexpr float L2_10000 = 13.287712379549449f;

    // supE -> featsM[s][0..255]
    if (t < 256) {
        int sidx = supidx[s];
        float se = 0.f;
        if (t < 252) {
            int c  = t / 84;
            int rr = t - c * 84;
            int f  = (rr < 42) ? rr : rr - 42;
            float coord = pos[3 * sidx + c];
            float ang = coord * exp2f(-(float)f * (L2_10000 / 42.f));
            se = (rr < 42) ? __sinf(ang) : __cosf(ang);
        }
        featsM[s * (2 * H) + t] = se;
    }

    if (t < KNB) {
        float4 v = rfM[s * KNB + t];
        rf[t][0] = v.x; rf[t][1] = v.y; rf[t][2] = v.z; rf[t][3] = v.w;
    }
    __syncthreads();

#pragma unroll
    for (int n = 0; n < 8; n++) {
        int item = t + n * 512;
        int f = item & 31;
        int c = (item >> 5) & 3;
        int k = item >> 7;
        float ang = rf[k][c] * exp2f(-(float)f * (L2_10000 / 32.f));
        int swz = (k & 7) << 3;
        msg[((k << 8) | (c * 64 + f))      ^ swz] = f2bf(__sinf(ang));
        msg[((k << 8) | (c * 64 + 32 + f)) ^ swz] = f2bf(__cosf(ang));
    }
    __syncthreads();

    // MFMA GEMM1: wave w owns j-rows [32w, 32w+32)
    {
        const int lr = lane & 15;
        const int lg = lane >> 4;
        f32x4 acc00 = {0,0,0,0}, acc01 = {0,0,0,0};
        f32x4 acc10 = {0,0,0,0}, acc11 = {0,0,0,0};
#pragma unroll
        for (int kk = 0; kk < 8; kk++) {
            const int i0 = kk * 32 + lg * 8;
            bf16x8 a0 = *(const bf16x8*)(W1t + ((32 * w      + lr) << 8) + i0);
            bf16x8 a1 = *(const bf16x8*)(W1t + ((32 * w + 16 + lr) << 8) + i0);
            const int swz = (lr & 7) << 3;
            bf16x8 b0  = *(const bf16x8*)(msg + ((( lr       << 8) | i0) ^ swz));
            bf16x8 b1v = *(const bf16x8*)(msg + ((((lr + 16) << 8) | i0) ^ swz));
            acc00 = __builtin_amdgcn_mfma_f32_16x16x32_bf16(a0, b0,  acc00, 0, 0, 0);
            acc01 = __builtin_amdgcn_mfma_f32_16x16x32_bf16(a0, b1v, acc01, 0, 0, 0);
            acc10 = __builtin_amdgcn_mfma_f32_16x16x32_bf16(a1, b0,  acc10, 0, 0, 0);
            acc11 = __builtin_amdgcn_mfma_f32_16x16x32_bf16(a1, b1v, acc11, 0, 0, 0);
        }
        float part[8];
#pragma unroll
        for (int mm = 0; mm < 2; mm++)
#pragma unroll
            for (int r = 0; r < 4; r++) {
                int j = 32 * w + 16 * mm + 4 * lg + r;
                float bj = b1[j];
                float h0 = (mm == 0 ? acc00[r] : acc10[r]) + bj;
                float h1 = (mm == 0 ? acc01[r] : acc11[r]) + bj;
                part[mm * 4 + r] = gelu_fast(h0) + gelu_fast(h1);
            }
#pragma unroll
        for (int off = 1; off < 16; off <<= 1)
#pragma unroll
            for (int u = 0; u < 8; u++)
                part[u] += __shfl_xor(part[u], off);
        if (lr == 0) {
#pragma unroll
            for (int u = 0; u < 8; u++) {
                int mm = u >> 2, r = u & 3;
                hb[32 * w + 16 * mm + 4 * lg + r] = part[u] * (1.0f / 32.0f);
            }
        }
    }
    __syncthreads();   // hb ready; msg dead -> p2

    // W2 matvec: group g handles i in [32g,32g+32); lane covers 4 j's
    {
        const int j4 = lane * 4;
        const int ib = w * 32;
        float4 a = {0.f, 0.f, 0.f, 0.f};
#pragma unroll 4
        for (int i = 0; i < 32; i++) {
            float hv = hb[ib + i];
            float4 wv = *(const float4*)&W2[(ib + i) * H + j4];
            a.x = fmaf(hv, wv.x, a.x); a.y = fmaf(hv, wv.y, a.y);
            a.z = fmaf(hv, wv.z, a.z); a.w = fmaf(hv, wv.w, a.w);
        }
        *(float4*)&p2[w * 256 + j4] = a;
    }
    __syncthreads();
    if (t < 256) {
        float agg = b2[t];
#pragma unroll
        for (int g = 0; g < 8; g++) agg += p2[g * 256 + t];
        featsM[s * (2 * H) + H + t] = agg;
    }
}

// ---- kernel B: C[M x N] = A[M x K] @ B[K x N] + bias, fp32 tiled 32x32 ----
__global__ __launch_bounds__(256)
void gemm_bias(const float* __restrict__ A, const float* __restrict__ B,
               const float* __restrict__ bias, float* __restrict__ C,
               int K, int N, int ldc)
{
    __shared__ float As[32][36];
    __shared__ float Bs[32][36];
    const int t  = threadIdx.x;
    const int bm = blockIdx.x, bn = blockIdx.y;
    const int tx = t & 15, ty = t >> 4;
    const int lr = t >> 3, lc = (t & 7) * 4;

    float acc[2][2] = {{0.f, 0.f}, {0.f, 0.f}};

    for (int kk = 0; kk < K; kk += 32) {
        float4 av = *(const float4*)&A[(bm * 32 + lr) * K + kk + lc];
        float4 bv = *(const float4*)&B[(kk + lr) * N + bn * 32 + lc];
        *(float4*)&As[lr][lc] = av;
        *(float4*)&Bs[lr][lc] = bv;
        __syncthreads();
#pragma unroll
        for (int k = 0; k < 32; k++) {
            float a0 = As[2 * ty][k], a1 = As[2 * ty + 1][k];
            float2 b01 = *(const float2*)&Bs[k][2 * tx];
            acc[0][0] += a0 * b01.x; acc[0][1] += a0 * b01.y;
            acc[1][0] += a1 * b01.x; acc[1][1] += a1 * b01.y;
        }
        __syncthreads();
    }
#pragma unroll
    for (int u = 0; u < 2; u++) {
        int row = bm * 32 + 2 * ty + u;
        int col = bn * 32 + 2 * tx;
        C[row * ldc + col]     = acc[u][0] + bias[col];
        C[row * ldc + col + 1] = acc[u][1] + bias[col + 1];
    }
}

extern "C" void kernel_launch(void* const* d_in, const int* in_sizes, int n_in,
                              void* d_out, int out_size, void* d_ws, size_t ws_size,
                              hipStream_t stream) {
    const float* pos = (const float*)d_in[0];
    const int*   sup = (const int*)d_in[1];
    const float* W1  = (const float*)d_in[2];
    const float* b1  = (const float*)d_in[3];
    const float* W2  = (const float*)d_in[4];
    const float* b2  = (const float*)d_in[5];
    const float* Wp  = (const float*)d_in[6];
    const float* bp  = (const float*)d_in[7];

    const int N = in_sizes[0] / 3;
    const int S = in_sizes[1];
    float* out = (float*)d_out;

    char* ws = (char*)d_ws;
    ushort* W1t     = (ushort*)ws;                      // 128 KB
    float4* pos4s   = (float4*)(ws + (128 << 10));      // 4096*32*16 = 2 MB
    int*    origidx = (int*)(ws + (2176 << 10));        // 512 KB
    int*    cellcnt = (int*)(ws + (2688 << 10));        // 4097 ints
    int*    ovfidx  = (int*)(ws + (2708 << 10));        // 1 KB
    float4* ovfpos  = (float4*)(ws + (2712 << 10));     // 4 KB
    float*  featsM  = (float*)(ws + (2720 << 10));      // 2 MB
    float4* rfM     = (float4*)(ws + (4768 << 10));     // 512 KB

    hipMemsetAsync(cellcnt, 0, 4097 * sizeof(int), stream);
    prep<<<64 + (N + 255) / 256, 256, 0, stream>>>(W1, pos, N, W1t, pos4s,
                                                   origidx, cellcnt, ovfidx, ovfpos);
    wave_select<<<(S + 3) / 4, 256, 0, stream>>>(pos, pos4s, origidx, cellcnt,
                                                 ovfidx, ovfpos, sup, S, rfM);
    embed_gemm1<<<S, 512, 0, stream>>>(rfM, W1t, b1, W2, b2, pos, sup, featsM);
    gemm_bias<<<dim3(S / 32, H / 32), 256, 0, stream>>>(featsM, Wp, bp, out,
                                                        2 * H, H, H);
}

// Round 12
// 133.117 us; speedup vs baseline: 1.1136x; 1.1136x over previous
//
#include <hip/hip_runtime.h>
#include <hip/hip_bf16.h>
#include <math.h>

typedef short bf16x8 __attribute__((ext_vector_type(8)));
typedef float f32x4  __attribute__((ext_vector_type(4)));

constexpr int   H     = 256;
constexpr int   KNB   = 32;
constexpr int   GC    = 16;      // bin-grid cells per dim
constexpr float HINV  = 1.6f;    // GC / 10.0
constexpr float HCEL  = 0.625f;  // 10.0 / GC
constexpr int   SLOTS = 32;      // slots per cell (avg fill ~12.2; overflow spills)
constexpr int   OCAP  = 256;     // overflow list capacity
constexpr int   WCAP  = 256;     // per-wave candidate list capacity

__device__ __forceinline__ ushort f2bf(float x) {
    unsigned u = __float_as_uint(x);
    u += 0x7FFF + ((u >> 16) & 1);
    return (ushort)(u >> 16);
}

__device__ __forceinline__ float gelu_fast(float x) {
    float u = 0.7978845608028654f * (x + 0.044715f * x * x * x);
    float t = exp2f(-2.885390081777927f * u);
    return x / (1.0f + t);
}

__device__ __forceinline__ int cell_of(float x, float y, float z) {
    int cx = min(GC - 1, max(0, (int)(x * HINV)));
    int cy = min(GC - 1, max(0, (int)(y * HINV)));
    int cz = min(GC - 1, max(0, (int)(z * HINV)));
    return (cz * GC + cy) * GC + cx;
}

// ---- prep: W1t transpose (blocks 0..63); slotted scatter (rest) ----
__global__ __launch_bounds__(256)
void prep(const float* __restrict__ W1, const float* __restrict__ pos, int N,
          ushort* __restrict__ W1t, float4* __restrict__ pos4s,
          int* __restrict__ origidx, int* __restrict__ cellcnt,
          int* __restrict__ ovfidx, float4* __restrict__ ovfpos) {
    const int b = blockIdx.x;
    if (b < 64) {
        __shared__ float tile[32][33];
        const int ti = b >> 3, tj = b & 7;
        const int r  = threadIdx.x >> 5, c = threadIdx.x & 31;
#pragma unroll
        for (int rr = r; rr < 32; rr += 8)
            tile[rr][c] = W1[(ti * 32 + rr) * H + tj * 32 + c];
        __syncthreads();
#pragma unroll
        for (int rr = r; rr < 32; rr += 8) {
            int j = tj * 32 + rr;
            W1t[j * H + ti * 32 + c] = f2bf(tile[c][rr]);
        }
    } else {
        int i = (b - 64) * 256 + threadIdx.x;
        if (i < N) {
            float x = pos[3 * i], y = pos[3 * i + 1], z = pos[3 * i + 2];
            float4 P = make_float4(x, y, z, 0.f);
            int c = cell_of(x, y, z);
            int slot = atomicAdd(&cellcnt[c], 1);
            if (slot < SLOTS) {
                pos4s[c * SLOTS + slot] = P;
                origidx[c * SLOTS + slot] = i;
            } else {
                int o = atomicAdd(&cellcnt[4096], 1);
                if (o < OCAP) { ovfpos[o] = P; ovfidx[o] = i; }
            }
        }
    }
}

// ---- wave-synchronous exact kNN, batched-load version ----
__global__ __launch_bounds__(256)
void wave_select(const float* __restrict__ pos,
                 const float4* __restrict__ pos4s,
                 const int* __restrict__ origidx,
                 const int* __restrict__ cellcnt,
                 const int* __restrict__ ovfidx, const float4* __restrict__ ovfpos,
                 const int* __restrict__ supidx, int S,
                 float4* __restrict__ rfM)
{
    __shared__ int   cumB[4][128];
    __shared__ int   cidB[4][128];
    __shared__ float wd2B[4][WCAP];
    __shared__ int   widB[4][WCAP];

    const int lane = threadIdx.x & 63;
    const int w    = threadIdx.x >> 6;
    const int s    = blockIdx.x * 4 + w;
    if (s >= S) return;

    int*   cum = cumB[w];
    int*   cid = cidB[w];
    float* wd2 = wd2B[w];
    int*   wid = widB[w];

    const int sidx = supidx[s];
    const float sx = pos[3 * sidx], sy = pos[3 * sidx + 1], sz = pos[3 * sidx + 2];

    const int scx = min(GC - 1, max(0, (int)(sx * HINV)));
    const int scy = min(GC - 1, max(0, (int)(sy * HINV)));
    const int scz = min(GC - 1, max(0, (int)(sz * HINV)));

    // ---- window: slot k = 2*lane + sl over 5^3 = 125 cells; batched loads ----
    float amax[2], mind[2];
    int   cnt_[2], cbase[2];
#pragma unroll
    for (int sl = 0; sl < 2; sl++) {
        int ci = 2 * lane + sl;
        int X = scx - 2 + ci % 5;
        int Y = scy - 2 + (ci / 5) % 5;
        int Z = scz - 2 + ci / 25;
        bool val = (ci < 125) && X >= 0 && X < GC && Y >= 0 && Y < GC && Z >= 0 && Z < GC;
        int cell = val ? (Z * GC + Y) * GC + X : 0;
        int cn = val ? min(cellcnt[cell], SLOTS) : 0;
        float am = 1e30f, mn = 1e30f;
        if (cn > 0) {
            float lx = X * HCEL, ly = Y * HCEL, lz = Z * HCEL;
            float mx = fmaxf(fabsf(sx - lx), fabsf(lx + HCEL - sx));
            float my = fmaxf(fabsf(sy - ly), fabsf(ly + HCEL - sy));
            float mz = fmaxf(fabsf(sz - lz), fabsf(lz + HCEL - sz));
            am = mx * mx + my * my + mz * mz;
            float ddx = fmaxf(fmaxf(lx - sx, sx - (lx + HCEL)), 0.f);
            float ddy = fmaxf(fmaxf(ly - sy, sy - (ly + HCEL)), 0.f);
            float ddz = fmaxf(fmaxf(lz - sz, sz - (lz + HCEL)), 0.f);
            mn = ddx * ddx + ddy * ddy + ddz * ddz;
        }
        amax[sl] = am; mind[sl] = mn;
        cnt_[sl] = cn; cbase[sl] = cell * SLOTS;
    }

    // ---- tau_cells: smallest amax with cumulative count >= 32 (weighted rank) ----
    int S0 = 0, S1 = 0;
    const int k0 = 2 * lane, k1 = 2 * lane + 1;
    for (int j = 0; j < 64; j++) {
        float a0 = __shfl(amax[0], j); int n0 = __shfl(cnt_[0], j);
        float a1 = __shfl(amax[1], j); int n1 = __shfl(cnt_[1], j);
        int j0 = 2 * j, j1 = 2 * j + 1;
        S0 += ((a0 < amax[0]) || (a0 == amax[0] && j0 < k0)) ? n0 : 0;
        S0 += ((a1 < amax[0]) || (a1 == amax[0] && j1 < k0)) ? n1 : 0;
        S1 += ((a0 < amax[1]) || (a0 == amax[1] && j0 < k1)) ? n0 : 0;
        S1 += ((a1 < amax[1]) || (a1 == amax[1] && j1 < k1)) ? n1 : 0;
    }
    float tc = 1e30f;
    if (S0 < KNB && KNB <= S0 + cnt_[0]) tc = amax[0];
    if (S1 < KNB && KNB <= S1 + cnt_[1]) tc = fminf(tc, amax[1]);
#pragma unroll
    for (int off = 32; off; off >>= 1) tc = fminf(tc, __shfl_xor(tc, off));
    const float tau_cells = (tc < 1e29f) ? tc : 301.f;

    // ---- phase 1: all points of p1 cells (amax <= tau_cells); >=32 guaranteed ----
    bool p1f[2];
    int n1c[2];
#pragma unroll
    for (int sl = 0; sl < 2; sl++) {
        p1f[sl] = (cnt_[sl] > 0) && (amax[sl] <= tau_cells);
        n1c[sl] = p1f[sl] ? cnt_[sl] : 0;
    }
    {
        int tot01 = n1c[0] + n1c[1];
        int run = tot01;
#pragma unroll
        for (int off = 1; off < 64; off <<= 1) {
            int x = __shfl_up(run, off);
            if (lane >= off) run += x;
        }
        int excl = run - tot01;
        cum[k0] = excl + n1c[0];
        cum[k1] = excl + tot01;
        cid[k0] = cbase[0];
        cid[k1] = cbase[1];
    }
    const int m1 = min(__shfl(cum[127], 0) * 0 + cum[127], WCAP);  // cum ready (in-wave LDS)
    // NOTE: cum[127] read after writes by same wave; compiler inserts lgkmcnt wait.
    for (int j0 = 0; j0 < m1; j0 += 64) {
        int j = j0 + lane;
        if (j < m1) {
            int lo = 0;
#pragma unroll
            for (int st = 64; st; st >>= 1) {
                int nlo = lo + st;
                if (nlo <= 128 && cum[nlo - 1] <= j) lo = nlo;
            }
            int off = j - (lo ? cum[lo - 1] : 0);
            int base = cid[lo] + off;
            float4 P = pos4s[base];
            float dx = sx - P.x, dy = sy - P.y, dz = sz - P.z;
            wd2[j] = dx * dx + dy * dy + dz * dz;
            wid[j] = origidx[base];
        }
    }

    // chunked shuffle-rank helper over wd2/wid[0..mm)
    float mv[4]; int mi[4]; int rk[4]; int myn;
    auto ranked = [&](int mm) {
        myn = 0;
        for (int u = lane; u < mm; u += 64) {
            mv[myn] = wd2[u]; mi[myn] = wid[u]; rk[myn] = 0; myn++;
        }
        int nch = (mm + 63) >> 6;
        for (int c = 0; c < nch; c++) {
            int idx = c * 64 + lane;
            bool lv = idx < mm;
            float rv = lv ? wd2[idx] : 1e30f;
            int   ri = lv ? wid[idx] : 0x7fffffff;
            for (int j = 0; j < 64; j++) {
                float bv = __shfl(rv, j);
                int   bi = __shfl(ri, j);
#pragma unroll
                for (int k = 0; k < 4; k++)
                    if (k < myn) rk[k] += (bv < mv[k]) || (bv == mv[k] && bi < mi[k]);
            }
        }
    };

    // ---- tau* = exact 32nd-smallest of phase-1 set ----
    float tstar;
    {
        ranked(m1);
        float ts = 1e30f;
#pragma unroll
        for (int k = 0; k < 4; k++)
            if (k < myn && rk[k] == KNB - 1) ts = mv[k];
#pragma unroll
        for (int off = 32; off; off >>= 1) ts = fminf(ts, __shfl_xor(ts, off));
        tstar = (ts < 1e29f) ? ts : tau_cells;
    }
    const float tauG = tstar * 1.000001f + 1e-6f;

    // ---- phase 2: ball-box cells of tau*, excluding p1 cells ----
    const float Rb = sqrtf(tauG);
    const int bx0 = max(0, (int)floorf((sx - Rb) * HINV));
    const int bx1 = min(GC - 1, (int)floorf((sx + Rb) * HINV));
    const int by0 = max(0, (int)floorf((sy - Rb) * HINV));
    const int by1 = min(GC - 1, (int)floorf((sy + Rb) * HINV));
    const int bz0 = max(0, (int)floorf((sz - Rb) * HINV));
    const int bz1 = min(GC - 1, (int)floorf((sz + Rb) * HINV));
    const int nbx = bx1 - bx0 + 1, nby = by1 - by0 + 1, nbz = bz1 - bz0 + 1;
    const int ncb = min(nbx * nby * nbz, 128);

    int n2c[2], cb2[2];
#pragma unroll
    for (int sl = 0; sl < 2; sl++) {
        int ci = 2 * lane + sl;
        bool cv = ci < ncb;
        int X = bx0 + ci % nbx, rem = ci / nbx;
        int Y = by0 + rem % nby, Z = bz0 + rem / nby;
        int cell = cv ? (Z * GC + Y) * GC + X : 0;
        int cn = cv ? min(cellcnt[cell], SLOTS) : 0;
        bool keep = false;
        if (cn > 0) {
            float lx = X * HCEL, ly = Y * HCEL, lz = Z * HCEL;
            float ddx = fmaxf(fmaxf(lx - sx, sx - (lx + HCEL)), 0.f);
            float ddy = fmaxf(fmaxf(ly - sy, sy - (ly + HCEL)), 0.f);
            float ddz = fmaxf(fmaxf(lz - sz, sz - (lz + HCEL)), 0.f);
            keep = (ddx * ddx + ddy * ddy + ddz * ddz) <= tauG;
            if (keep) {
                // exclude p1 cells (bitwise-identical amax predicate)
                bool inWin = (X >= scx - 2 && X <= scx + 2 &&
                              Y >= scy - 2 && Y <= scy + 2 &&
                              Z >= scz - 2 && Z <= scz + 2);
                if (inWin) {
                    float mx = fmaxf(fabsf(sx - lx), fabsf(lx + HCEL - sx));
                    float my = fmaxf(fabsf(sy - ly), fabsf(ly + HCEL - sy));
                    float mz = fmaxf(fabsf(sz - lz), fabsf(lz + HCEL - sz));
                    float am = mx * mx + my * my + mz * mz;
                    if (am <= tau_cells) keep = false;
                }
            }
        }
        n2c[sl] = keep ? cn : 0;
        cb2[sl] = cell * SLOTS;
    }
    {
        int tot01 = n2c[0] + n2c[1];
        int run = tot01;
#pragma unroll
        for (int off = 1; off < 64; off <<= 1) {
            int x = __shfl_up(run, off);
            if (lane >= off) run += x;
        }
        int excl = run - tot01;
        cum[k0] = excl + n2c[0];
        cum[k1] = excl + tot01;
        cid[k0] = cb2[0];
        cid[k1] = cb2[1];
    }
    int m = m1;
    const int tot2 = cum[127];
    for (int j0 = 0; j0 < tot2; j0 += 64) {
        int j = j0 + lane;
        bool act = false; float d2 = 0.f; int oi = 0;
        if (j < tot2) {
            int lo = 0;
#pragma unroll
            for (int st = 64; st; st >>= 1) {
                int nlo = lo + st;
                if (nlo <= 128 && cum[nlo - 1] <= j) lo = nlo;
            }
            int off = j - (lo ? cum[lo - 1] : 0);
            int base = cid[lo] + off;
            float4 P = pos4s[base];
            float dx = sx - P.x, dy = sy - P.y, dz = sz - P.z;
            d2 = dx * dx + dy * dy + dz * dz;
            if (d2 <= tauG) { act = true; oi = origidx[base]; }
        }
        unsigned long long mk = __ballot(act);
        int ofs = __popcll(mk & ((1ull << lane) - 1ull));
        if (act && m + ofs < WCAP) { wd2[m + ofs] = d2; wid[m + ofs] = oi; }
        m = min(m + (int)__popcll(mk), WCAP);
    }
    // overflow spill list (expected empty)
    {
        int no = min(cellcnt[4096], OCAP);
        for (int j0 = 0; j0 < no; j0 += 64) {
            int j = j0 + lane;
            bool act = j < no;
            float d2 = 0.f; int oi = 0;
            if (act) {
                float4 P = ovfpos[j];
                float dx = sx - P.x, dy = sy - P.y, dz = sz - P.z;
                d2 = dx * dx + dy * dy + dz * dz;
                act = d2 <= tauG;
                if (act) oi = ovfidx[j];
            }
            unsigned long long mk = __ballot(act);
            int ofs = __popcll(mk & ((1ull << lane) - 1ull));
            if (act && m + ofs < WCAP) { wd2[m + ofs] = d2; wid[m + ofs] = oi; }
            m = min(m + (int)__popcll(mk), WCAP);
        }
    }

    // ---- final exact rank -> top-32 -> rel features ----
    {
        ranked(m);
#pragma unroll
        for (int k = 0; k < 4; k++) {
            if (k < myn && rk[k] < KNB) {
                int ni = mi[k];
                float px = pos[3 * ni], py = pos[3 * ni + 1], pz = pos[3 * ni + 2];
                float rx = sx - px, ry = sy - py, rz = sz - pz;
                float dd = sqrtf(rx * rx + ry * ry + rz * rz);
                rfM[s * KNB + rk[k]] = make_float4(rx, ry, rz, dd);
            }
        }
    }
}

// ---- K3: supE + sincos embed + MFMA GEMM1 + gelu/mean + W2 matvec ----
__global__ __launch_bounds__(512, 4)
void embed_gemm1(const float4* __restrict__ rfM,
                 const ushort* __restrict__ W1t, const float* __restrict__ b1,
                 const float* __restrict__ W2, const float* __restrict__ b2,
                 const float* __restrict__ pos, const int* __restrict__ supidx,
                 float* __restrict__ featsM)
{
    __shared__ __align__(16) char pool[16384];   // msg bf16[32][256] then p2 f32[8][256]
    ushort* msg = (ushort*)pool;
    float*  p2  = (float*)pool;
    __shared__ float rf[KNB][5];
    __shared__ float hb[H];

    const int s    = blockIdx.x;
    const int t    = threadIdx.x;
    const int lane = t & 63;
    const int w    = t >> 6;

    constexpr float L2_10000 = 13.287712379549449f;

    if (t < 256) {
        int sidx = supidx[s];
        float se = 0.f;
        if (t < 252) {
            int c  = t / 84;
            int rr = t - c * 84;
            int f  = (rr < 42) ? rr : rr - 42;
            float coord = pos[3 * sidx + c];
            float ang = coord * exp2f(-(float)f * (L2_10000 / 42.f));
            se = (rr < 42) ? __sinf(ang) : __cosf(ang);
        }
        featsM[s * (2 * H) + t] = se;
    }

    if (t < KNB) {
        float4 v = rfM[s * KNB + t];
        rf[t][0] = v.x; rf[t][1] = v.y; rf[t][2] = v.z; rf[t][3] = v.w;
    }
    __syncthreads();

#pragma unroll
    for (int n = 0; n < 8; n++) {
        int item = t + n * 512;
        int f = item & 31;
        int c = (item >> 5) & 3;
        int k = item >> 7;
        float ang = rf[k][c] * exp2f(-(float)f * (L2_10000 / 32.f));
        int swz = (k & 7) << 3;
        msg[((k << 8) | (c * 64 + f))      ^ swz] = f2bf(__sinf(ang));
        msg[((k << 8) | (c * 64 + 32 + f)) ^ swz] = f2bf(__cosf(ang));
    }
    __syncthreads();

    {
        const int lr = lane & 15;
        const int lg = lane >> 4;
        f32x4 acc00 = {0,0,0,0}, acc01 = {0,0,0,0};
        f32x4 acc10 = {0,0,0,0}, acc11 = {0,0,0,0};
#pragma unroll
        for (int kk = 0; kk < 8; kk++) {
            const int i0 = kk * 32 + lg * 8;
            bf16x8 a0 = *(const bf16x8*)(W1t + ((32 * w      + lr) << 8) + i0);
            bf16x8 a1 = *(const bf16x8*)(W1t + ((32 * w + 16 + lr) << 8) + i0);
            const int swz = (lr & 7) << 3;
            bf16x8 b0  = *(const bf16x8*)(msg + ((( lr       << 8) | i0) ^ swz));
            bf16x8 b1v = *(const bf16x8*)(msg + ((((lr + 16) << 8) | i0) ^ swz));
            acc00 = __builtin_amdgcn_mfma_f32_16x16x32_bf16(a0, b0,  acc00, 0, 0, 0);
            acc01 = __builtin_amdgcn_mfma_f32_16x16x32_bf16(a0, b1v, acc01, 0, 0, 0);
            acc10 = __builtin_amdgcn_mfma_f32_16x16x32_bf16(a1, b0,  acc10, 0, 0, 0);
            acc11 = __builtin_amdgcn_mfma_f32_16x16x32_bf16(a1, b1v, acc11, 0, 0, 0);
        }
        float part[8];
#pragma unroll
        for (int mm = 0; mm < 2; mm++)
#pragma unroll
            for (int r = 0; r < 4; r++) {
                int j = 32 * w + 16 * mm + 4 * lg + r;
                float bj = b1[j];
                float h0 = (mm == 0 ? acc00[r] : acc10[r]) + bj;
                float h1 = (mm == 0 ? acc01[r] : acc11[r]) + bj;
                part[mm * 4 + r] = gelu_fast(h0) + gelu_fast(h1);
            }
#pragma unroll
        for (int off = 1; off < 16; off <<= 1)
#pragma unroll
            for (int u = 0; u < 8; u++)
                part[u] += __shfl_xor(part[u], off);
        if (lr == 0) {
#pragma unroll
            for (int u = 0; u < 8; u++) {
                int mm = u >> 2, r = u & 3;
                hb[32 * w + 16 * mm + 4 * lg + r] = part[u] * (1.0f / 32.0f);
            }
        }
    }
    __syncthreads();   // hb ready; msg dead -> p2

    {
        const int j4 = lane * 4;
        const int ib = w * 32;
        float4 a = {0.f, 0.f, 0.f, 0.f};
#pragma unroll 4
        for (int i = 0; i < 32; i++) {
            float hv = hb[ib + i];
            float4 wv = *(const float4*)&W2[(ib + i) * H + j4];
            a.x = fmaf(hv, wv.x, a.x); a.y = fmaf(hv, wv.y, a.y);
            a.z = fmaf(hv, wv.z, a.z); a.w = fmaf(hv, wv.w, a.w);
        }
        *(float4*)&p2[w * 256 + j4] = a;
    }
    __syncthreads();
    if (t < 256) {
        float agg = b2[t];
#pragma unroll
        for (int g = 0; g < 8; g++) agg += p2[g * 256 + t];
        featsM[s * (2 * H) + H + t] = agg;
    }
}

// ---- kernel B: C[M x N] = A[M x K] @ B[K x N] + bias, fp32 tiled 32x32 ----
__global__ __launch_bounds__(256)
void gemm_bias(const float* __restrict__ A, const float* __restrict__ B,
               const float* __restrict__ bias, float* __restrict__ C,
               int K, int N, int ldc)
{
    __shared__ float As[32][36];
    __shared__ float Bs[32][36];
    const int t  = threadIdx.x;
    const int bm = blockIdx.x, bn = blockIdx.y;
    const int tx = t & 15, ty = t >> 4;
    const int lr = t >> 3, lc = (t & 7) * 4;

    float acc[2][2] = {{0.f, 0.f}, {0.f, 0.f}};

    for (int kk = 0; kk < K; kk += 32) {
        float4 av = *(const float4*)&A[(bm * 32 + lr) * K + kk + lc];
        float4 bv = *(const float4*)&B[(kk + lr) * N + bn * 32 + lc];
        *(float4*)&As[lr][lc] = av;
        *(float4*)&Bs[lr][lc] = bv;
        __syncthreads();
#pragma unroll
        for (int k = 0; k < 32; k++) {
            float a0 = As[2 * ty][k], a1 = As[2 * ty + 1][k];
            float2 b01 = *(const float2*)&Bs[k][2 * tx];
            acc[0][0] += a0 * b01.x; acc[0][1] += a0 * b01.y;
            acc[1][0] += a1 * b01.x; acc[1][1] += a1 * b01.y;
        }
        __syncthreads();
    }
#pragma unroll
    for (int u = 0; u < 2; u++) {
        int row = bm * 32 + 2 * ty + u;
        int col = bn * 32 + 2 * tx;
        C[row * ldc + col]     = acc[u][0] + bias[col];
        C[row * ldc + col + 1] = acc[u][1] + bias[col + 1];
    }
}

extern "C" void kernel_launch(void* const* d_in, const int* in_sizes, int n_in,
                              void* d_out, int out_size, void* d_ws, size_t ws_size,
                              hipStream_t stream) {
    const float* pos = (const float*)d_in[0];
    const int*   sup = (const int*)d_in[1];
    const float* W1  = (const float*)d_in[2];
    const float* b1  = (const float*)d_in[3];
    const float* W2  = (const float*)d_in[4];
    const float* b2  = (const float*)d_in[5];
    const float* Wp  = (const float*)d_in[6];
    const float* bp  = (const float*)d_in[7];

    const int N = in_sizes[0] / 3;
    const int S = in_sizes[1];
    float* out = (float*)d_out;

    char* ws = (char*)d_ws;
    ushort* W1t     = (ushort*)ws;                      // 128 KB
    float4* pos4s   = (float4*)(ws + (128 << 10));      // 4096*32*16 = 2 MB
    int*    origidx = (int*)(ws + (2176 << 10));        // 512 KB
    int*    cellcnt = (int*)(ws + (2688 << 10));        // 4097 ints
    int*    ovfidx  = (int*)(ws + (2708 << 10));        // 1 KB
    float4* ovfpos  = (float4*)(ws + (2712 << 10));     // 4 KB
    float*  featsM  = (float*)(ws + (2720 << 10));      // 2 MB
    float4* rfM     = (float4*)(ws + (4768 << 10));     // 512 KB

    hipMemsetAsync(cellcnt, 0, 4097 * sizeof(int), stream);
    prep<<<64 + (N + 255) / 256, 256, 0, stream>>>(W1, pos, N, W1t, pos4s,
                                                   origidx, cellcnt, ovfidx, ovfpos);
    wave_select<<<(S + 3) / 4, 256, 0, stream>>>(pos, pos4s, origidx, cellcnt,
                                                 ovfidx, ovfpos, sup, S, rfM);
    embed_gemm1<<<S, 512, 0, stream>>>(rfM, W1t, b1, W2, b2, pos, sup, featsM);
    gemm_bias<<<dim3(S / 32, H / 32), 256, 0, stream>>>(featsM, Wp, bp, out,
                                                        2 * H, H, H);
}

// Round 14
// 83.658 us; speedup vs baseline: 1.7720x; 1.5912x over previous
//
#include <hip/hip_runtime.h>
#include <hip/hip_bf16.h>
#include <math.h>

typedef short bf16x8 __attribute__((ext_vector_type(8)));
typedef float f32x4  __attribute__((ext_vector_type(4)));

constexpr int   H     = 256;
constexpr int   KNB   = 32;
constexpr int   GC    = 16;      // bin-grid cells per dim
constexpr float HINV  = 1.6f;    // GC / 10.0
constexpr float HCEL  = 0.625f;  // 10.0 / GC
constexpr int   SLOTS = 32;      // slots per cell (avg fill ~12.2; overflow spills)
constexpr int   OCAP  = 256;     // overflow list capacity
constexpr int   CAP   = 512;     // candidate buffer

__device__ __forceinline__ ushort f2bf(float x) {
    unsigned u = __float_as_uint(x);
    u += 0x7FFF + ((u >> 16) & 1);
    return (ushort)(u >> 16);
}

__device__ __forceinline__ float gelu_fast(float x) {
    float u = 0.7978845608028654f * (x + 0.044715f * x * x * x);
    float t = exp2f(-2.885390081777927f * u);
    return x / (1.0f + t);
}

__device__ __forceinline__ int cell_of(float x, float y, float z) {
    int cx = min(GC - 1, max(0, (int)(x * HINV)));
    int cy = min(GC - 1, max(0, (int)(y * HINV)));
    int cz = min(GC - 1, max(0, (int)(z * HINV)));
    return (cz * GC + cy) * GC + cx;
}

// ---- prep: W1t transpose (blocks 0..63); slotted scatter (rest) ----
__global__ __launch_bounds__(256)
void prep(const float* __restrict__ W1, const float* __restrict__ pos, int N,
          ushort* __restrict__ W1t, float4* __restrict__ pos4s,
          int* __restrict__ origidx, int* __restrict__ cellcnt,
          int* __restrict__ ovfidx, float4* __restrict__ ovfpos) {
    const int b = blockIdx.x;
    if (b < 64) {
        __shared__ float tile[32][33];
        const int ti = b >> 3, tj = b & 7;
        const int r  = threadIdx.x >> 5, c = threadIdx.x & 31;
#pragma unroll
        for (int rr = r; rr < 32; rr += 8)
            tile[rr][c] = W1[(ti * 32 + rr) * H + tj * 32 + c];
        __syncthreads();
#pragma unroll
        for (int rr = r; rr < 32; rr += 8) {
            int j = tj * 32 + rr;
            W1t[j * H + ti * 32 + c] = f2bf(tile[c][rr]);
        }
    } else {
        int i = (b - 64) * 256 + threadIdx.x;
        if (i < N) {
            float x = pos[3 * i], y = pos[3 * i + 1], z = pos[3 * i + 2];
            float4 P = make_float4(x, y, z, 0.f);
            int c = cell_of(x, y, z);
            int slot = atomicAdd(&cellcnt[c], 1);
            if (slot < SLOTS) {
                pos4s[c * SLOTS + slot] = P;
                origidx[c * SLOTS + slot] = i;
            } else {
                int o = atomicAdd(&cellcnt[4096], 1);   // overflow count
                if (o < OCAP) { ovfpos[o] = P; ovfidx[o] = i; }
            }
        }
    }
}

// ---- fused: cell-count tau -> phase1 exact tau* -> phase2 -> top-32 ->
//      embed -> MFMA GEMM1 -> gelu/mean -> W2 matvec -> featsM ----
__global__ __launch_bounds__(256, 4)
void fused_knn_mlp(const float* __restrict__ pos,
                   const float4* __restrict__ pos4s,
                   const int* __restrict__ origidx,
                   const int* __restrict__ cellcnt,
                   const int* __restrict__ ovfidx, const float4* __restrict__ ovfpos,
                   const int* __restrict__ supidx,
                   const ushort* __restrict__ W1t, const float* __restrict__ b1,
                   const float* __restrict__ W2, const float* __restrict__ b2,
                   float* __restrict__ featsM)
{
    // 16 KB pool, time-multiplexed:
    //  select: amaxd[128]@0 | acnt[128]@512 | ccell[256]@1024 | ccnt[256]@2048 |
    //    cmnd[256]@3072 | cpre[256]@4096 | d2buf[512]@5120 | obuf[512]@7168 |
    //    pxb[512]@9216 | pyb[512]@11264 | pzb[512]@13312
    //  mlp:    msg bf16[32][256]@0 (16 KB, XOR-swizzled)  then p2 f32[1024]@0
    __shared__ __align__(16) char pool[16384];
    float* amaxd = (float*)pool;
    int*   acnt  = (int*)(pool + 512);
    int*   ccell = (int*)(pool + 1024);
    int*   ccnt  = (int*)(pool + 2048);
    float* cmnd  = (float*)(pool + 3072);
    int*   cpre  = (int*)(pool + 4096);
    float* d2buf = (float*)(pool + 5120);
    int*   obuf  = (int*)(pool + 7168);
    float* pxb   = (float*)(pool + 9216);
    float* pyb   = (float*)(pool + 11264);
    float* pzb   = (float*)(pool + 13312);
    ushort* msg  = (ushort*)pool;
    float*  p2   = (float*)pool;

    __shared__ float rf[KNB][5];
    __shared__ int   selo[KNB];    // slot index of each top-32 candidate
    __shared__ float hb[H];
    __shared__ int   wsum[4];
    __shared__ float tau2_sh, tau32_sh;
    __shared__ int   cnt_sh, ncl;

    const int s    = blockIdx.x;
    const int t    = threadIdx.x;
    const int lane = t & 63;
    const int w    = t >> 6;

    const int sidx = supidx[s];
    const float sx = pos[3 * sidx], sy = pos[3 * sidx + 1], sz = pos[3 * sidx + 2];

    constexpr float L2_10000 = 13.287712379549449f;

    if (t == 0) { ncl = 0; tau2_sh = 301.f; }

    // ---- stage A: issue cellcnt window loads FIRST (latency hidden by supE) ----
    const int scx = min(GC - 1, max(0, (int)(sx * HINV)));
    const int scy = min(GC - 1, max(0, (int)(sy * HINV)));
    const int scz = min(GC - 1, max(0, (int)(sz * HINV)));
    const int ax0 = max(0, scx - 2), ax1 = min(GC - 1, scx + 2);
    const int ay0 = max(0, scy - 2), ay1 = min(GC - 1, scy + 2);
    const int az0 = max(0, scz - 2), az1 = min(GC - 1, scz + 2);
    const int anx = ax1 - ax0 + 1, any_ = ay1 - ay0 + 1, anz = az1 - az0 + 1;
    const int an  = anx * any_ * anz;    // <= 125
    for (int ci = t; ci < an; ci += 256) {
        int X = ax0 + ci % anx, rem = ci / anx;
        int Y = ay0 + rem % any_, Z = az0 + rem / any_;
        int cell = (Z * GC + Y) * GC + X;
        acnt[ci] = min(cellcnt[cell], SLOTS);
        float lx = X * HCEL, ly = Y * HCEL, lz = Z * HCEL;
        float mx = fmaxf(fabsf(sx - lx), fabsf(lx + HCEL - sx));
        float my = fmaxf(fabsf(sy - ly), fabsf(ly + HCEL - sy));
        float mz = fmaxf(fabsf(sz - lz), fabsf(lz + HCEL - sz));
        amaxd[ci] = mx * mx + my * my + mz * mz;
    }

    // supE embed -> featsM[s][0..255]  (VALU work overlapping the loads above)
    {
        float se = 0.f;
        if (t < 252) {
            int c  = t / 84;
            int rr = t - c * 84;
            int f  = (rr < 42) ? rr : rr - 42;
            float coord = (c == 0) ? sx : ((c == 1) ? sy : sz);
            float ang = coord * exp2f(-(float)f * (L2_10000 / 42.f));
            se = (rr < 42) ? __sinf(ang) : __cosf(ang);
        }
        featsM[s * (2 * H) + t] = se;
    }
    __syncthreads();
    // smallest amax whose cumulative count reaches 32 => >=32 pts within tau
    for (int ci = t; ci < an; ci += 256) {
        float myv = amaxd[ci];
        int Sc = 0;
        for (int j = 0; j < an; j++) {
            bool less = (amaxd[j] < myv) || (amaxd[j] == myv && j < ci);
            Sc += less ? acnt[j] : 0;
        }
        if (Sc < KNB && KNB <= Sc + acnt[ci]) tau2_sh = myv;
    }
    __syncthreads();
    const float tau2 = tau2_sh;
    const float R2 = tau2 + 1e-3f;
    const float R  = sqrtf(R2);
    if (t == 0) tau32_sh = R2;   // fallback if phase1 < 32

    // ---- stage B: build ball-cell list (cell, cnt|p1flag, mind2) ----
    const int bx0 = max(0, (int)floorf((sx - R) * HINV));
    const int bx1 = min(GC - 1, (int)floorf((sx + R) * HINV));
    const int by0 = max(0, (int)floorf((sy - R) * HINV));
    const int by1 = min(GC - 1, (int)floorf((sy + R) * HINV));
    const int bz0 = max(0, (int)floorf((sz - R) * HINV));
    const int bz1 = min(GC - 1, (int)floorf((sz + R) * HINV));
    const bool inwin = (bx0 >= ax0 && bx1 <= ax1 && by0 >= ay0 && by1 <= ay1 &&
                        bz0 >= az0 && bz1 <= az1);
    if (inwin) {
        // common case: ball cells within the loaded 5^3 window -> NO global reloads
        for (int ci = t; ci < an; ci += 256) {
            int cn = acnt[ci];
            if (cn == 0) continue;
            int X = ax0 + ci % anx, rem = ci / anx;
            int Y = ay0 + rem % any_, Z = az0 + rem / any_;
            float lx = X * HCEL, ly = Y * HCEL, lz = Z * HCEL;
            float ddx = fmaxf(fmaxf(lx - sx, sx - (lx + HCEL)), 0.f);
            float ddy = fmaxf(fmaxf(ly - sy, sy - (ly + HCEL)), 0.f);
            float ddz = fmaxf(fmaxf(lz - sz, sz - (lz + HCEL)), 0.f);
            float mnd = ddx * ddx + ddy * ddy + ddz * ddz;
            if (mnd > R2) continue;
            int p1 = (amaxd[ci] <= tau2) ? 1 : 0;
            int cell = (Z * GC + Y) * GC + X;
            int sl = atomicAdd(&ncl, 1);
            if (sl < 256) { ccell[sl] = cell; ccnt[sl] = cn | (p1 << 8); cmnd[sl] = mnd; }
        }
    } else {
        // rare: ball exceeds window -> original reload path (exact, validated)
        const int nbx = bx1 - bx0 + 1, nby = by1 - by0 + 1, nbz = bz1 - bz0 + 1;
        const int ncb = nbx * nby * nbz;
        for (int ci = t; ci < ncb; ci += 256) {
            int X = bx0 + ci % nbx, rem = ci / nbx;
            int Y = by0 + rem % nby, Z = bz0 + rem / nby;
            float lx = X * HCEL, ly = Y * HCEL, lz = Z * HCEL;
            float ddx = fmaxf(fmaxf(lx - sx, sx - (lx + HCEL)), 0.f);
            float ddy = fmaxf(fmaxf(ly - sy, sy - (ly + HCEL)), 0.f);
            float ddz = fmaxf(fmaxf(lz - sz, sz - (lz + HCEL)), 0.f);
            float mnd = ddx * ddx + ddy * ddy + ddz * ddz;
            if (mnd > R2) continue;
            int cell = (Z * GC + Y) * GC + X;
            int cn = min(cellcnt[cell], SLOTS);
            if (cn == 0) continue;
            float mx = fmaxf(fabsf(sx - lx), fabsf(lx + HCEL - sx));
            float my = fmaxf(fabsf(sy - ly), fabsf(ly + HCEL - sy));
            float mz = fmaxf(fabsf(sz - lz), fabsf(lz + HCEL - sz));
            float amx = mx * mx + my * my + mz * mz;
            int p1 = (amx <= tau2) ? 1 : 0;
            int sl = atomicAdd(&ncl, 1);
            if (sl < 256) { ccell[sl] = cell; ccnt[sl] = cn | (p1 << 8); cmnd[sl] = mnd; }
        }
    }
    __syncthreads();
    const int nclc = min(ncl, 256);

    // shuffle-based inclusive prefix over 256 masked counts (2 barriers)
    auto build_prefix = [&](int phase, float tlim) -> int {
        int v = 0;
        if (t < nclc) {
            int cc = ccnt[t];
            int cn = cc & 0xff;
            int p1 = cc >> 8;
            v = (phase == 1) ? (p1 ? cn : 0)
                             : ((!p1 && cmnd[t] <= tlim) ? cn : 0);
        }
#pragma unroll
        for (int off = 1; off < 64; off <<= 1) {
            int x = __shfl_up(v, off);
            if (lane >= off) v += x;
        }
        if (lane == 63) wsum[w] = v;
        __syncthreads();
        int add = 0;
#pragma unroll
        for (int j = 0; j < 4; j++) if (j < w) add += wsum[j];
        v += add;
        cpre[t] = v;
        __syncthreads();
        return cpre[255];
    };
    auto bsearch = [&](int j) -> int {
        int lo = 0;
#pragma unroll
        for (int st = 128; st; st >>= 1) {
            int nlo = lo + st;
            if (nlo <= 256 && cpre[nlo - 1] <= j) lo = nlo;
        }
        return lo;
    };

    // ---- phase 1: gather ALL points of P1 cells (dense, no atomics) ----
    const int tot1 = build_prefix(1, 0.f);
    const int M1 = min(tot1, CAP);
    for (int j0 = 0; j0 < M1; j0 += 256) {
        int j = j0 + t;
        if (j < M1) {
            int lo = bsearch(j);
            int off = j - (lo ? cpre[lo - 1] : 0);
            int u = ccell[lo] * SLOTS + off;
            float4 P = pos4s[u];
            float dx = sx - P.x, dy = sy - P.y, dz = sz - P.z;
            d2buf[j] = dx * dx + dy * dy + dz * dz;
            obuf[j]  = origidx[u];
            pxb[j] = P.x; pyb[j] = P.y; pzb[j] = P.z;
        }
    }
    const int Mp1 = (M1 + 3) & ~3;
    for (int u = M1 + t; u < Mp1; u += 256) { d2buf[u] = INFINITY; obuf[u] = 0x7fffffff; }
    if (t == 0) cnt_sh = M1;
    __syncthreads();

    // exact 32nd-smallest of phase-1 set -> tau* (<= tau2 by construction)
    for (int u = t; u < M1; u += 256) {
        float myv = d2buf[u];
        int   myo = obuf[u];
        int rank = 0;
        for (int v2 = 0; v2 < Mp1; v2 += 4) {
            float4 dv = *(const float4*)&d2buf[v2];
            int4   iv = *(const int4*)&obuf[v2];
            rank += (dv.x < myv) || (dv.x == myv && iv.x < myo);
            rank += (dv.y < myv) || (dv.y == myv && iv.y < myo);
            rank += (dv.z < myv) || (dv.z == myv && iv.z < myo);
            rank += (dv.w < myv) || (dv.w == myv && iv.w < myo);
        }
        if (rank == KNB - 1) tau32_sh = myv;
    }
    __syncthreads();
    const float tau32 = tau32_sh;

    // ---- phase 2: cells with mind2 <= tau*, filter d2 <= tau* ----
    const int tot2 = build_prefix(2, tau32);
    for (int j0 = 0; j0 < tot2; j0 += 256) {
        int j = j0 + t;
        bool pass = false; float pd2 = 0.f; int po = 0; float qx = 0, qy = 0, qz = 0;
        if (j < tot2) {
            int lo = bsearch(j);
            int off = j - (lo ? cpre[lo - 1] : 0);
            int u = ccell[lo] * SLOTS + off;
            float4 P = pos4s[u];
            float dx = sx - P.x, dy = sy - P.y, dz = sz - P.z;
            pd2 = dx * dx + dy * dy + dz * dz;
            if (pd2 <= tau32) { pass = true; po = origidx[u]; qx = P.x; qy = P.y; qz = P.z; }
        }
        unsigned long long m = __ballot(pass);
        if (m) {
            int ldr = __ffsll(m) - 1;
            int base = 0;
            if (lane == ldr) base = atomicAdd(&cnt_sh, __popcll(m));
            base = __shfl(base, ldr);
            if (pass) {
                int slp = base + __popcll(m & ((1ull << lane) - 1ull));
                if (slp < CAP) {
                    d2buf[slp] = pd2; obuf[slp] = po;
                    pxb[slp] = qx; pyb[slp] = qy; pzb[slp] = qz;
                }
            }
        }
    }
    // overflow spill list (expected empty)
    {
        int no = min(cellcnt[4096], OCAP);
        for (int j = t; j < no; j += 256) {
            float4 P = ovfpos[j];
            float dx = sx - P.x, dy = sy - P.y, dz = sz - P.z;
            float pd2 = dx * dx + dy * dy + dz * dz;
            if (pd2 <= tau32) {
                int slp = atomicAdd(&cnt_sh, 1);
                if (slp < CAP) {
                    d2buf[slp] = pd2; obuf[slp] = ovfidx[j];
                    pxb[slp] = P.x; pyb[slp] = P.y; pzb[slp] = P.z;
                }
            }
        }
    }
    __syncthreads();
    const int M = min(cnt_sh, CAP);
    const int Mpad = (M + 3) & ~3;
    for (int u = M + t; u < Mpad; u += 256) { d2buf[u] = INFINITY; obuf[u] = 0x7fffffff; }
    __syncthreads();

    // final exact rank-merge -> top-32 (store winning SLOT, not index)
    for (int u = t; u < M; u += 256) {
        float myv = d2buf[u];
        int   myo = obuf[u];
        int rank = 0;
        for (int v2 = 0; v2 < Mpad; v2 += 4) {
            float4 dv = *(const float4*)&d2buf[v2];
            int4   iv = *(const int4*)&obuf[v2];
            rank += (dv.x < myv) || (dv.x == myv && iv.x < myo);
            rank += (dv.y < myv) || (dv.y == myv && iv.y < myo);
            rank += (dv.z < myv) || (dv.z == myv && iv.z < myo);
            rank += (dv.w < myv) || (dv.w == myv && iv.w < myo);
        }
        if (rank < KNB) selo[rank] = u;
    }
    __syncthreads();
    if (t < KNB) {
        int u = selo[t];
        float rx = sx - pxb[u], ry = sy - pyb[u], rz = sz - pzb[u];
        float dd = sqrtf(d2buf[u]);
        rf[t][0] = rx; rf[t][1] = ry; rf[t][2] = rz; rf[t][3] = dd;
    }
    __syncthreads();   // select stage dead; msg takes pool

    // ---- sincos embed -> msg[k][i] bf16, row-XOR swizzle ----
#pragma unroll
    for (int n = 0; n < 16; n++) {
        int item = t + n * 256;
        int f = item & 31;
        int c = (item >> 5) & 3;
        int k = item >> 7;
        float ang = rf[k][c] * exp2f(-(float)f * (L2_10000 / 32.f));
        int swz = (k & 7) << 3;
        msg[((k << 8) | (c * 64 + f))      ^ swz] = f2bf(__sinf(ang));
        msg[((k << 8) | (c * 64 + 32 + f)) ^ swz] = f2bf(__cosf(ang));
    }
    __syncthreads();

    // ---- MFMA GEMM1: wave w owns j-rows [64w, 64w+64) ----
    {
        const int lr = lane & 15;
        const int lg = lane >> 4;
        f32x4 acc[4][2];
#pragma unroll
        for (int mt = 0; mt < 4; mt++)
#pragma unroll
            for (int nt = 0; nt < 2; nt++) acc[mt][nt] = (f32x4){0, 0, 0, 0};
#pragma unroll
        for (int kk = 0; kk < 8; kk++) {
            const int i0 = kk * 32 + lg * 8;
            const int swz = (lr & 7) << 3;
            bf16x8 b0  = *(const bf16x8*)(msg + ((( lr       << 8) | i0) ^ swz));
            bf16x8 b1v = *(const bf16x8*)(msg + ((((lr + 16) << 8) | i0) ^ swz));
#pragma unroll
            for (int mt = 0; mt < 4; mt++) {
                bf16x8 a = *(const bf16x8*)(W1t + ((64 * w + 16 * mt + lr) << 8) + i0);
                acc[mt][0] = __builtin_amdgcn_mfma_f32_16x16x32_bf16(a, b0,  acc[mt][0], 0, 0, 0);
                acc[mt][1] = __builtin_amdgcn_mfma_f32_16x16x32_bf16(a, b1v, acc[mt][1], 0, 0, 0);
            }
        }
        float part[16];
#pragma unroll
        for (int mt = 0; mt < 4; mt++)
#pragma unroll
            for (int r = 0; r < 4; r++) {
                int j = 64 * w + 16 * mt + 4 * lg + r;
                float bj = b1[j];
                part[mt * 4 + r] = gelu_fast(acc[mt][0][r] + bj) + gelu_fast(acc[mt][1][r] + bj);
            }
#pragma unroll
        for (int off = 1; off < 16; off <<= 1)
#pragma unroll
            for (int u = 0; u < 16; u++)
                part[u] += __shfl_xor(part[u], off);
        if (lr == 0) {
#pragma unroll
            for (int u = 0; u < 16; u++) {
                int mt = u >> 2, r = u & 3;
                hb[64 * w + 16 * mt + 4 * lg + r] = part[u] * (1.0f / 32.0f);
            }
        }
    }
    __syncthreads();   // hb ready; msg dead -> p2

    // ---- W2 matvec: agg = hb @ W2 + b2 -> featsM[s][256..511] ----
    {
        const int g  = t >> 6;
        const int j4 = (t & 63) * 4;
        const int ib = g * 64;
        float4 a = {0.f, 0.f, 0.f, 0.f};
        for (int i = 0; i < 64; i++) {
            float hv = hb[ib + i];
            float4 wv = *(const float4*)&W2[(ib + i) * H + j4];
            a.x = fmaf(hv, wv.x, a.x); a.y = fmaf(hv, wv.y, a.y);
            a.z = fmaf(hv, wv.z, a.z); a.w = fmaf(hv, wv.w, a.w);
        }
        *(float4*)&p2[g * 256 + j4] = a;
    }
    __syncthreads();
    {
        float agg = p2[t] + p2[256 + t] + p2[512 + t] + p2[768 + t] + b2[t];
        featsM[s * (2 * H) + H + t] = agg;
    }
}

// ---- kernel B: C[M x N] = A[M x K] @ B[K x N] + bias, fp32 tiled 32x32 ----
__global__ __launch_bounds__(256)
void gemm_bias(const float* __restrict__ A, const float* __restrict__ B,
               const float* __restrict__ bias, float* __restrict__ C,
               int K, int N, int ldc)
{
    __shared__ float As[32][36];
    __shared__ float Bs[32][36];
    const int t  = threadIdx.x;
    const int bm = blockIdx.x, bn = blockIdx.y;
    const int tx = t & 15, ty = t >> 4;
    const int lr = t >> 3, lc = (t & 7) * 4;

    float acc[2][2] = {{0.f, 0.f}, {0.f, 0.f}};

    for (int kk = 0; kk < K; kk += 32) {
        float4 av = *(const float4*)&A[(bm * 32 + lr) * K + kk + lc];
        float4 bv = *(const float4*)&B[(kk + lr) * N + bn * 32 + lc];
        *(float4*)&As[lr][lc] = av;
        *(float4*)&Bs[lr][lc] = bv;
        __syncthreads();
#pragma unroll
        for (int k = 0; k < 32; k++) {
            float a0 = As[2 * ty][k], a1 = As[2 * ty + 1][k];
            float2 b01 = *(const float2*)&Bs[k][2 * tx];
            acc[0][0] += a0 * b01.x; acc[0][1] += a0 * b01.y;
            acc[1][0] += a1 * b01.x; acc[1][1] += a1 * b01.y;
        }
        __syncthreads();
    }
#pragma unroll
    for (int u = 0; u < 2; u++) {
        int row = bm * 32 + 2 * ty + u;
        int col = bn * 32 + 2 * tx;
        C[row * ldc + col]     = acc[u][0] + bias[col];
        C[row * ldc + col + 1] = acc[u][1] + bias[col + 1];
    }
}

extern "C" void kernel_launch(void* const* d_in, const int* in_sizes, int n_in,
                              void* d_out, int out_size, void* d_ws, size_t ws_size,
                              hipStream_t stream) {
    const float* pos = (const float*)d_in[0];
    const int*   sup = (const int*)d_in[1];
    const float* W1  = (const float*)d_in[2];
    const float* b1  = (const float*)d_in[3];
    const float* W2  = (const float*)d_in[4];
    const float* b2  = (const float*)d_in[5];
    const float* Wp  = (const float*)d_in[6];
    const float* bp  = (const float*)d_in[7];

    const int N = in_sizes[0] / 3;
    const int S = in_sizes[1];
    float* out = (float*)d_out;

    char* ws = (char*)d_ws;
    ushort* W1t     = (ushort*)ws;                      // 128 KB
    float4* pos4s   = (float4*)(ws + (128 << 10));      // 4096*32*16 = 2 MB
    int*    origidx = (int*)(ws + (2176 << 10));        // 512 KB
    int*    cellcnt = (int*)(ws + (2688 << 10));        // 4097 ints
    int*    ovfidx  = (int*)(ws + (2708 << 10));        // 1 KB
    float4* ovfpos  = (float4*)(ws + (2712 << 10));     // 4 KB
    float*  featsM  = (float*)(ws + (2720 << 10));      // 2 MB

    hipMemsetAsync(cellcnt, 0, 4097 * sizeof(int), stream);
    prep<<<64 + (N + 255) / 256, 256, 0, stream>>>(W1, pos, N, W1t, pos4s,
                                                   origidx, cellcnt, ovfidx, ovfpos);
    fused_knn_mlp<<<S, 256, 0, stream>>>(pos, pos4s, origidx, cellcnt,
                                         ovfidx, ovfpos, sup,
                                         W1t, b1, W2, b2, featsM);
    gemm_bias<<<dim3(S / 32, H / 32), 256, 0, stream>>>(featsM, Wp, bp, out,
                                                        2 * H, H, H);
}

// Round 15
// 83.010 us; speedup vs baseline: 1.7858x; 1.0078x over previous
//
#include <hip/hip_runtime.h>
#include <hip/hip_bf16.h>
#include <math.h>

typedef short bf16x8 __attribute__((ext_vector_type(8)));
typedef float f32x4  __attribute__((ext_vector_type(4)));

constexpr int   H     = 256;
constexpr int   KNB   = 32;
constexpr int   TPB   = 512;     // 8 waves/block -> 32 waves/CU resident
constexpr int   GC    = 16;      // bin-grid cells per dim
constexpr float HINV  = 1.6f;    // GC / 10.0
constexpr float HCEL  = 0.625f;  // 10.0 / GC
constexpr int   SLOTS = 32;      // slots per cell (avg fill ~12.2; overflow spills)
constexpr int   OCAP  = 256;     // overflow list capacity
constexpr int   CAP   = 512;     // candidate buffer

__device__ __forceinline__ ushort f2bf(float x) {
    unsigned u = __float_as_uint(x);
    u += 0x7FFF + ((u >> 16) & 1);
    return (ushort)(u >> 16);
}

__device__ __forceinline__ float gelu_fast(float x) {
    float u = 0.7978845608028654f * (x + 0.044715f * x * x * x);
    float t = exp2f(-2.885390081777927f * u);
    return x / (1.0f + t);
}

__device__ __forceinline__ int cell_of(float x, float y, float z) {
    int cx = min(GC - 1, max(0, (int)(x * HINV)));
    int cy = min(GC - 1, max(0, (int)(y * HINV)));
    int cz = min(GC - 1, max(0, (int)(z * HINV)));
    return (cz * GC + cy) * GC + cx;
}

// ---- prep: W1t transpose (blocks 0..63); slotted scatter (rest) ----
__global__ __launch_bounds__(256)
void prep(const float* __restrict__ W1, const float* __restrict__ pos, int N,
          ushort* __restrict__ W1t, float4* __restrict__ pos4s,
          int* __restrict__ origidx, int* __restrict__ cellcnt,
          int* __restrict__ ovfidx, float4* __restrict__ ovfpos) {
    const int b = blockIdx.x;
    if (b < 64) {
        __shared__ float tile[32][33];
        const int ti = b >> 3, tj = b & 7;
        const int r  = threadIdx.x >> 5, c = threadIdx.x & 31;
#pragma unroll
        for (int rr = r; rr < 32; rr += 8)
            tile[rr][c] = W1[(ti * 32 + rr) * H + tj * 32 + c];
        __syncthreads();
#pragma unroll
        for (int rr = r; rr < 32; rr += 8) {
            int j = tj * 32 + rr;
            W1t[j * H + ti * 32 + c] = f2bf(tile[c][rr]);
        }
    } else {
        int i = (b - 64) * 256 + threadIdx.x;
        if (i < N) {
            float x = pos[3 * i], y = pos[3 * i + 1], z = pos[3 * i + 2];
            float4 P = make_float4(x, y, z, 0.f);
            int c = cell_of(x, y, z);
            int slot = atomicAdd(&cellcnt[c], 1);
            if (slot < SLOTS) {
                pos4s[c * SLOTS + slot] = P;
                origidx[c * SLOTS + slot] = i;
            } else {
                int o = atomicAdd(&cellcnt[4096], 1);   // overflow count
                if (o < OCAP) { ovfpos[o] = P; ovfidx[o] = i; }
            }
        }
    }
}

// ---- fused: cell-count tau -> phase1 exact tau* -> phase2 -> top-32 ->
//      embed -> MFMA GEMM1 -> gelu/mean -> W2 matvec -> featsM ----
__global__ __launch_bounds__(TPB, 8)
void fused_knn_mlp(const float* __restrict__ pos,
                   const float4* __restrict__ pos4s,
                   const int* __restrict__ origidx,
                   const int* __restrict__ cellcnt,
                   const int* __restrict__ ovfidx, const float4* __restrict__ ovfpos,
                   const int* __restrict__ supidx,
                   const ushort* __restrict__ W1t, const float* __restrict__ b1,
                   const float* __restrict__ W2, const float* __restrict__ b2,
                   float* __restrict__ featsM)
{
    // 16 KB pool, time-multiplexed:
    //  select: amaxd[128]@0 | acnt[128]@512 | ccell[256]@1024 | ccnt[256]@2048 |
    //    cmnd[256]@3072 | cpre[256]@4096 | d2buf[512]@5120 | obuf[512]@7168 |
    //    pxb[512]@9216 | pyb[512]@11264 | pzb[512]@13312
    //  mlp:    msg bf16[32][256]@0 (16 KB, XOR-swizzled)  then p2 f32[8][256]@0
    __shared__ __align__(16) char pool[16384];
    float* amaxd = (float*)pool;
    int*   acnt  = (int*)(pool + 512);
    int*   ccell = (int*)(pool + 1024);
    int*   ccnt  = (int*)(pool + 2048);
    float* cmnd  = (float*)(pool + 3072);
    int*   cpre  = (int*)(pool + 4096);
    float* d2buf = (float*)(pool + 5120);
    int*   obuf  = (int*)(pool + 7168);
    float* pxb   = (float*)(pool + 9216);
    float* pyb   = (float*)(pool + 11264);
    float* pzb   = (float*)(pool + 13312);
    ushort* msg  = (ushort*)pool;
    float*  p2   = (float*)pool;

    __shared__ float rf[KNB][5];
    __shared__ int   selo[KNB];    // slot index of each top-32 candidate
    __shared__ float hb[H];
    __shared__ int   wsum[4];
    __shared__ float tau2_sh, tau32_sh;
    __shared__ int   cnt_sh, ncl;

    const int s    = blockIdx.x;
    const int t    = threadIdx.x;
    const int lane = t & 63;
    const int w    = t >> 6;       // wave 0..7

    const int sidx = supidx[s];
    const float sx = pos[3 * sidx], sy = pos[3 * sidx + 1], sz = pos[3 * sidx + 2];

    constexpr float L2_10000 = 13.287712379549449f;

    if (t == 0) { ncl = 0; tau2_sh = 301.f; }

    // ---- stage A: issue cellcnt window loads FIRST (latency hidden by supE) ----
    const int scx = min(GC - 1, max(0, (int)(sx * HINV)));
    const int scy = min(GC - 1, max(0, (int)(sy * HINV)));
    const int scz = min(GC - 1, max(0, (int)(sz * HINV)));
    const int ax0 = max(0, scx - 2), ax1 = min(GC - 1, scx + 2);
    const int ay0 = max(0, scy - 2), ay1 = min(GC - 1, scy + 2);
    const int az0 = max(0, scz - 2), az1 = min(GC - 1, scz + 2);
    const int anx = ax1 - ax0 + 1, any_ = ay1 - ay0 + 1, anz = az1 - az0 + 1;
    const int an  = anx * any_ * anz;    // <= 125
    if (t < an) {
        int ci = t;
        int X = ax0 + ci % anx, rem = ci / anx;
        int Y = ay0 + rem % any_, Z = az0 + rem / any_;
        int cell = (Z * GC + Y) * GC + X;
        acnt[ci] = min(cellcnt[cell], SLOTS);
        float lx = X * HCEL, ly = Y * HCEL, lz = Z * HCEL;
        float mx = fmaxf(fabsf(sx - lx), fabsf(lx + HCEL - sx));
        float my = fmaxf(fabsf(sy - ly), fabsf(ly + HCEL - sy));
        float mz = fmaxf(fabsf(sz - lz), fabsf(lz + HCEL - sz));
        amaxd[ci] = mx * mx + my * my + mz * mz;
    }

    // supE embed -> featsM[s][0..255]  (VALU work overlapping the loads above)
    if (t < 256) {
        float se = 0.f;
        if (t < 252) {
            int c  = t / 84;
            int rr = t - c * 84;
            int f  = (rr < 42) ? rr : rr - 42;
            float coord = (c == 0) ? sx : ((c == 1) ? sy : sz);
            float ang = coord * exp2f(-(float)f * (L2_10000 / 42.f));
            se = (rr < 42) ? __sinf(ang) : __cosf(ang);
        }
        featsM[s * (2 * H) + t] = se;
    }
    __syncthreads();
    // smallest amax whose cumulative count reaches 32 => >=32 pts within tau
    if (t < an) {
        int ci = t;
        float myv = amaxd[ci];
        int Sc = 0;
        for (int j = 0; j < an; j++) {
            bool less = (amaxd[j] < myv) || (amaxd[j] == myv && j < ci);
            Sc += less ? acnt[j] : 0;
        }
        if (Sc < KNB && KNB <= Sc + acnt[ci]) tau2_sh = myv;
    }
    __syncthreads();
    const float tau2 = tau2_sh;
    const float R2 = tau2 + 1e-3f;
    const float R  = sqrtf(R2);
    if (t == 0) tau32_sh = R2;   // fallback if phase1 < 32

    // ---- stage B: build ball-cell list (cell, cnt|p1flag, mind2) ----
    const int bx0 = max(0, (int)floorf((sx - R) * HINV));
    const int bx1 = min(GC - 1, (int)floorf((sx + R) * HINV));
    const int by0 = max(0, (int)floorf((sy - R) * HINV));
    const int by1 = min(GC - 1, (int)floorf((sy + R) * HINV));
    const int bz0 = max(0, (int)floorf((sz - R) * HINV));
    const int bz1 = min(GC - 1, (int)floorf((sz + R) * HINV));
    const bool inwin = (bx0 >= ax0 && bx1 <= ax1 && by0 >= ay0 && by1 <= ay1 &&
                        bz0 >= az0 && bz1 <= az1);
    if (inwin) {
        // common case: ball cells within the loaded 5^3 window -> NO global reloads
        if (t < an) {
            int ci = t;
            int cn = acnt[ci];
            if (cn > 0) {
                int X = ax0 + ci % anx, rem = ci / anx;
                int Y = ay0 + rem % any_, Z = az0 + rem / any_;
                float lx = X * HCEL, ly = Y * HCEL, lz = Z * HCEL;
                float ddx = fmaxf(fmaxf(lx - sx, sx - (lx + HCEL)), 0.f);
                float ddy = fmaxf(fmaxf(ly - sy, sy - (ly + HCEL)), 0.f);
                float ddz = fmaxf(fmaxf(lz - sz, sz - (lz + HCEL)), 0.f);
                float mnd = ddx * ddx + ddy * ddy + ddz * ddz;
                if (mnd <= R2) {
                    int p1 = (amaxd[ci] <= tau2) ? 1 : 0;
                    int cell = (Z * GC + Y) * GC + X;
                    int sl = atomicAdd(&ncl, 1);
                    if (sl < 256) { ccell[sl] = cell; ccnt[sl] = cn | (p1 << 8); cmnd[sl] = mnd; }
                }
            }
        }
    } else {
        // rare: ball exceeds window -> original reload path (exact, validated)
        const int nbx = bx1 - bx0 + 1, nby = by1 - by0 + 1, nbz = bz1 - bz0 + 1;
        const int ncb = nbx * nby * nbz;
        for (int ci = t; ci < ncb; ci += TPB) {
            int X = bx0 + ci % nbx, rem = ci / nbx;
            int Y = by0 + rem % nby, Z = bz0 + rem / nby;
            float lx = X * HCEL, ly = Y * HCEL, lz = Z * HCEL;
            float ddx = fmaxf(fmaxf(lx - sx, sx - (lx + HCEL)), 0.f);
            float ddy = fmaxf(fmaxf(ly - sy, sy - (ly + HCEL)), 0.f);
            float ddz = fmaxf(fmaxf(lz - sz, sz - (lz + HCEL)), 0.f);
            float mnd = ddx * ddx + ddy * ddy + ddz * ddz;
            if (mnd > R2) continue;
            int cell = (Z * GC + Y) * GC + X;
            int cn = min(cellcnt[cell], SLOTS);
            if (cn == 0) continue;
            float mx = fmaxf(fabsf(sx - lx), fabsf(lx + HCEL - sx));
            float my = fmaxf(fabsf(sy - ly), fabsf(ly + HCEL - sy));
            float mz = fmaxf(fabsf(sz - lz), fabsf(lz + HCEL - sz));
            float amx = mx * mx + my * my + mz * mz;
            int p1 = (amx <= tau2) ? 1 : 0;
            int sl = atomicAdd(&ncl, 1);
            if (sl < 256) { ccell[sl] = cell; ccnt[sl] = cn | (p1 << 8); cmnd[sl] = mnd; }
        }
    }
    __syncthreads();
    const int nclc = min(ncl, 256);

    // shuffle-based inclusive prefix over 256 masked counts (waves 0-3; 2 barriers)
    auto build_prefix = [&](int phase, float tlim) -> int {
        int v = 0;
        if (t < 256) {
            if (t < nclc) {
                int cc = ccnt[t];
                int cn = cc & 0xff;
                int p1 = cc >> 8;
                v = (phase == 1) ? (p1 ? cn : 0)
                                 : ((!p1 && cmnd[t] <= tlim) ? cn : 0);
            }
#pragma unroll
            for (int off = 1; off < 64; off <<= 1) {
                int x = __shfl_up(v, off);
                if (lane >= off) v += x;
            }
            if (lane == 63) wsum[w] = v;
        }
        __syncthreads();
        if (t < 256) {
            int add = 0;
#pragma unroll
            for (int j = 0; j < 4; j++) if (j < w) add += wsum[j];
            cpre[t] = v + add;
        }
        __syncthreads();
        return cpre[255];
    };
    auto bsearch = [&](int j) -> int {
        int lo = 0;
#pragma unroll
        for (int st = 128; st; st >>= 1) {
            int nlo = lo + st;
            if (nlo <= 256 && cpre[nlo - 1] <= j) lo = nlo;
        }
        return lo;
    };

    // ---- phase 1: gather ALL points of P1 cells (dense, no atomics) ----
    const int tot1 = build_prefix(1, 0.f);
    const int M1 = min(tot1, CAP);
    if (t < M1) {
        int j = t;
        int lo = bsearch(j);
        int off = j - (lo ? cpre[lo - 1] : 0);
        int u = ccell[lo] * SLOTS + off;
        float4 P = pos4s[u];
        float dx = sx - P.x, dy = sy - P.y, dz = sz - P.z;
        d2buf[j] = dx * dx + dy * dy + dz * dz;
        obuf[j]  = origidx[u];
        pxb[j] = P.x; pyb[j] = P.y; pzb[j] = P.z;
    }
    const int Mp1 = (M1 + 3) & ~3;
    if (M1 + t < Mp1) { d2buf[M1 + t] = INFINITY; obuf[M1 + t] = 0x7fffffff; }
    if (t == 0) cnt_sh = M1;
    __syncthreads();

    // exact 32nd-smallest of phase-1 set -> tau* (<= tau2 by construction)
    if (t < M1) {
        int u = t;
        float myv = d2buf[u];
        int   myo = obuf[u];
        int rank = 0;
        for (int v2 = 0; v2 < Mp1; v2 += 4) {
            float4 dv = *(const float4*)&d2buf[v2];
            int4   iv = *(const int4*)&obuf[v2];
            rank += (dv.x < myv) || (dv.x == myv && iv.x < myo);
            rank += (dv.y < myv) || (dv.y == myv && iv.y < myo);
            rank += (dv.z < myv) || (dv.z == myv && iv.z < myo);
            rank += (dv.w < myv) || (dv.w == myv && iv.w < myo);
        }
        if (rank == KNB - 1) tau32_sh = myv;
    }
    __syncthreads();
    const float tau32 = tau32_sh;

    // ---- phase 2: cells with mind2 <= tau*, filter d2 <= tau* ----
    const int tot2 = build_prefix(2, tau32);
    for (int j0 = 0; j0 < tot2; j0 += TPB) {
        int j = j0 + t;
        bool pass = false; float pd2 = 0.f; int po = 0; float qx = 0, qy = 0, qz = 0;
        if (j < tot2) {
            int lo = bsearch(j);
            int off = j - (lo ? cpre[lo - 1] : 0);
            int u = ccell[lo] * SLOTS + off;
            float4 P = pos4s[u];
            float dx = sx - P.x, dy = sy - P.y, dz = sz - P.z;
            pd2 = dx * dx + dy * dy + dz * dz;
            if (pd2 <= tau32) { pass = true; po = origidx[u]; qx = P.x; qy = P.y; qz = P.z; }
        }
        unsigned long long m = __ballot(pass);
        if (m) {
            int ldr = __ffsll(m) - 1;
            int base = 0;
            if (lane == ldr) base = atomicAdd(&cnt_sh, __popcll(m));
            base = __shfl(base, ldr);
            if (pass) {
                int slp = base + __popcll(m & ((1ull << lane) - 1ull));
                if (slp < CAP) {
                    d2buf[slp] = pd2; obuf[slp] = po;
                    pxb[slp] = qx; pyb[slp] = qy; pzb[slp] = qz;
                }
            }
        }
    }
    // overflow spill list (expected empty)
    {
        int no = min(cellcnt[4096], OCAP);
        for (int j = t; j < no; j += TPB) {
            float4 P = ovfpos[j];
            float dx = sx - P.x, dy = sy - P.y, dz = sz - P.z;
            float pd2 = dx * dx + dy * dy + dz * dz;
            if (pd2 <= tau32) {
                int slp = atomicAdd(&cnt_sh, 1);
                if (slp < CAP) {
                    d2buf[slp] = pd2; obuf[slp] = ovfidx[j];
                    pxb[slp] = P.x; pyb[slp] = P.y; pzb[slp] = P.z;
                }
            }
        }
    }
    __syncthreads();
    const int M = min(cnt_sh, CAP);
    const int Mpad = (M + 3) & ~3;
    if (M + t < Mpad) { d2buf[M + t] = INFINITY; obuf[M + t] = 0x7fffffff; }
    __syncthreads();

    // final exact rank-merge -> top-32 (store winning SLOT, not index)
    if (t < M) {
        int u = t;
        float myv = d2buf[u];
        int   myo = obuf[u];
        int rank = 0;
        for (int v2 = 0; v2 < Mpad; v2 += 4) {
            float4 dv = *(const float4*)&d2buf[v2];
            int4   iv = *(const int4*)&obuf[v2];
            rank += (dv.x < myv) || (dv.x == myv && iv.x < myo);
            rank += (dv.y < myv) || (dv.y == myv && iv.y < myo);
            rank += (dv.z < myv) || (dv.z == myv && iv.z < myo);
            rank += (dv.w < myv) || (dv.w == myv && iv.w < myo);
        }
        if (rank < KNB) selo[rank] = u;
    }
    __syncthreads();
    if (t < KNB) {
        int u = selo[t];
        float rx = sx - pxb[u], ry = sy - pyb[u], rz = sz - pzb[u];
        float dd = sqrtf(d2buf[u]);
        rf[t][0] = rx; rf[t][1] = ry; rf[t][2] = rz; rf[t][3] = dd;
    }
    __syncthreads();   // select stage dead; msg takes pool

    // ---- sincos embed -> msg[k][i] bf16, row-XOR swizzle ----
#pragma unroll
    for (int n = 0; n < 8; n++) {
        int item = t + n * TPB;
        int f = item & 31;
        int c = (item >> 5) & 3;
        int k = item >> 7;
        float ang = rf[k][c] * exp2f(-(float)f * (L2_10000 / 32.f));
        int swz = (k & 7) << 3;
        msg[((k << 8) | (c * 64 + f))      ^ swz] = f2bf(__sinf(ang));
        msg[((k << 8) | (c * 64 + 32 + f)) ^ swz] = f2bf(__cosf(ang));
    }
    __syncthreads();

    // ---- MFMA GEMM1: wave w owns j-rows [32w, 32w+32) (8-wave layout) ----
    {
        const int lr = lane & 15;
        const int lg = lane >> 4;
        f32x4 acc00 = {0,0,0,0}, acc01 = {0,0,0,0};
        f32x4 acc10 = {0,0,0,0}, acc11 = {0,0,0,0};
#pragma unroll
        for (int kk = 0; kk < 8; kk++) {
            const int i0 = kk * 32 + lg * 8;
            bf16x8 a0 = *(const bf16x8*)(W1t + ((32 * w      + lr) << 8) + i0);
            bf16x8 a1 = *(const bf16x8*)(W1t + ((32 * w + 16 + lr) << 8) + i0);
            const int swz = (lr & 7) << 3;
            bf16x8 b0  = *(const bf16x8*)(msg + ((( lr       << 8) | i0) ^ swz));
            bf16x8 b1v = *(const bf16x8*)(msg + ((((lr + 16) << 8) | i0) ^ swz));
            acc00 = __builtin_amdgcn_mfma_f32_16x16x32_bf16(a0, b0,  acc00, 0, 0, 0);
            acc01 = __builtin_amdgcn_mfma_f32_16x16x32_bf16(a0, b1v, acc01, 0, 0, 0);
            acc10 = __builtin_amdgcn_mfma_f32_16x16x32_bf16(a1, b0,  acc10, 0, 0, 0);
            acc11 = __builtin_amdgcn_mfma_f32_16x16x32_bf16(a1, b1v, acc11, 0, 0, 0);
        }
        float part[8];
#pragma unroll
        for (int mm = 0; mm < 2; mm++)
#pragma unroll
            for (int r = 0; r < 4; r++) {
                int j = 32 * w + 16 * mm + 4 * lg + r;
                float bj = b1[j];
                float h0 = (mm == 0 ? acc00[r] : acc10[r]) + bj;
                float h1 = (mm == 0 ? acc01[r] : acc11[r]) + bj;
                part[mm * 4 + r] = gelu_fast(h0) + gelu_fast(h1);
            }
#pragma unroll
        for (int off = 1; off < 16; off <<= 1)
#pragma unroll
            for (int u = 0; u < 8; u++)
                part[u] += __shfl_xor(part[u], off);
        if (lr == 0) {
#pragma unroll
            for (int u = 0; u < 8; u++) {
                int mm = u >> 2, r = u & 3;
                hb[32 * w + 16 * mm + 4 * lg + r] = part[u] * (1.0f / 32.0f);
            }
        }
    }
    __syncthreads();   // hb ready; msg dead -> p2

    // ---- W2 matvec: group w handles i in [32w,32w+32); lane covers 4 j's ----
    {
        const int j4 = lane * 4;
        const int ib = w * 32;
        float4 a = {0.f, 0.f, 0.f, 0.f};
#pragma unroll 4
        for (int i = 0; i < 32; i++) {
            float hv = hb[ib + i];
            float4 wv = *(const float4*)&W2[(ib + i) * H + j4];
            a.x = fmaf(hv, wv.x, a.x); a.y = fmaf(hv, wv.y, a.y);
            a.z = fmaf(hv, wv.z, a.z); a.w = fmaf(hv, wv.w, a.w);
        }
        *(float4*)&p2[w * 256 + j4] = a;
    }
    __syncthreads();
    if (t < 256) {
        float agg = b2[t];
#pragma unroll
        for (int g = 0; g < 8; g++) agg += p2[g * 256 + t];
        featsM[s * (2 * H) + H + t] = agg;
    }
}

// ---- kernel B: C[M x N] = A[M x K] @ B[K x N] + bias, fp32 tiled 32x32 ----
__global__ __launch_bounds__(256)
void gemm_bias(const float* __restrict__ A, const float* __restrict__ B,
               const float* __restrict__ bias, float* __restrict__ C,
               int K, int N, int ldc)
{
    __shared__ float As[32][36];
    __shared__ float Bs[32][36];
    const int t  = threadIdx.x;
    const int bm = blockIdx.x, bn = blockIdx.y;
    const int tx = t & 15, ty = t >> 4;
    const int lr = t >> 3, lc = (t & 7) * 4;

    float acc[2][2] = {{0.f, 0.f}, {0.f, 0.f}};

    for (int kk = 0; kk < K; kk += 32) {
        float4 av = *(const float4*)&A[(bm * 32 + lr) * K + kk + lc];
        float4 bv = *(const float4*)&B[(kk + lr) * N + bn * 32 + lc];
        *(float4*)&As[lr][lc] = av;
        *(float4*)&Bs[lr][lc] = bv;
        __syncthreads();
#pragma unroll
        for (int k = 0; k < 32; k++) {
            float a0 = As[2 * ty][k], a1 = As[2 * ty + 1][k];
            float2 b01 = *(const float2*)&Bs[k][2 * tx];
            acc[0][0] += a0 * b01.x; acc[0][1] += a0 * b01.y;
            acc[1][0] += a1 * b01.x; acc[1][1] += a1 * b01.y;
        }
        __syncthreads();
    }
#pragma unroll
    for (int u = 0; u < 2; u++) {
        int row = bm * 32 + 2 * ty + u;
        int col = bn * 32 + 2 * tx;
        C[row * ldc + col]     = acc[u][0] + bias[col];
        C[row * ldc + col + 1] = acc[u][1] + bias[col + 1];
    }
}

extern "C" void kernel_launch(void* const* d_in, const int* in_sizes, int n_in,
                              void* d_out, int out_size, void* d_ws, size_t ws_size,
                              hipStream_t stream) {
    const float* pos = (const float*)d_in[0];
    const int*   sup = (const int*)d_in[1];
    const float* W1  = (const float*)d_in[2];
    const float* b1  = (const float*)d_in[3];
    const float* W2  = (const float*)d_in[4];
    const float* b2  = (const float*)d_in[5];
    const float* Wp  = (const float*)d_in[6];
    const float* bp  = (const float*)d_in[7];

    const int N = in_sizes[0] / 3;
    const int S = in_sizes[1];
    float* out = (float*)d_out;

    char* ws = (char*)d_ws;
    ushort* W1t     = (ushort*)ws;                      // 128 KB
    float4* pos4s   = (float4*)(ws + (128 << 10));      // 4096*32*16 = 2 MB
    int*    origidx = (int*)(ws + (2176 << 10));        // 512 KB
    int*    cellcnt = (int*)(ws + (2688 << 10));        // 4097 ints
    int*    ovfidx  = (int*)(ws + (2708 << 10));        // 1 KB
    float4* ovfpos  = (float4*)(ws + (2712 << 10));     // 4 KB
    float*  featsM  = (float*)(ws + (2720 << 10));      // 2 MB

    hipMemsetAsync(cellcnt, 0, 4097 * sizeof(int), stream);
    prep<<<64 + (N + 255) / 256, 256, 0, stream>>>(W1, pos, N, W1t, pos4s,
                                                   origidx, cellcnt, ovfidx, ovfpos);
    fused_knn_mlp<<<S, TPB, 0, stream>>>(pos, pos4s, origidx, cellcnt,
                                         ovfidx, ovfpos, sup,
                                         W1t, b1, W2, b2, featsM);
    gemm_bias<<<dim3(S / 32, H / 32), 256, 0, stream>>>(featsM, Wp, bp, out,
                                                        2 * H, H, H);
}

// Round 16
// 80.935 us; speedup vs baseline: 1.8316x; 1.0256x over previous
//
#include <hip/hip_runtime.h>
#include <hip/hip_bf16.h>
#include <math.h>

typedef short bf16x8 __attribute__((ext_vector_type(8)));
typedef float f32x4  __attribute__((ext_vector_type(4)));

constexpr int   H     = 256;
constexpr int   KNB   = 32;
constexpr int   TPB   = 512;     // 8 waves/block
constexpr int   GC    = 16;      // bin-grid cells per dim
constexpr float HINV  = 1.6f;    // GC / 10.0
constexpr float HCEL  = 0.625f;  // 10.0 / GC
constexpr int   SLOTS = 32;      // slots per cell (avg fill ~12.2; overflow spills)
constexpr int   OCAP  = 256;     // overflow list capacity
constexpr int   CAP   = 512;     // candidate buffer

__device__ __forceinline__ ushort f2bf(float x) {
    unsigned u = __float_as_uint(x);
    u += 0x7FFF + ((u >> 16) & 1);
    return (ushort)(u >> 16);
}

__device__ __forceinline__ float bf2f(ushort u) {
    return __uint_as_float(((unsigned)u) << 16);
}

__device__ __forceinline__ float gelu_fast(float x) {
    float u = 0.7978845608028654f * (x + 0.044715f * x * x * x);
    float t = exp2f(-2.885390081777927f * u);
    return x / (1.0f + t);
}

__device__ __forceinline__ int cell_of(float x, float y, float z) {
    int cx = min(GC - 1, max(0, (int)(x * HINV)));
    int cy = min(GC - 1, max(0, (int)(y * HINV)));
    int cz = min(GC - 1, max(0, (int)(z * HINV)));
    return (cz * GC + cy) * GC + cx;
}

// ---- prep: W1t (b<64), Wpt transpose (64..191), W2 bf16 (192..255),
//      slotted scatter (256..) ----
__global__ __launch_bounds__(256)
void prep(const float* __restrict__ W1, const float* __restrict__ Wp,
          const float* __restrict__ W2, const float* __restrict__ pos, int N,
          ushort* __restrict__ W1t, ushort* __restrict__ Wpt,
          ushort* __restrict__ W2b, float4* __restrict__ pos4s,
          int* __restrict__ origidx, int* __restrict__ cellcnt,
          int* __restrict__ ovfidx, float4* __restrict__ ovfpos) {
    const int b = blockIdx.x;
    if (b < 64) {
        __shared__ float tile[32][33];
        const int ti = b >> 3, tj = b & 7;
        const int r  = threadIdx.x >> 5, c = threadIdx.x & 31;
#pragma unroll
        for (int rr = r; rr < 32; rr += 8)
            tile[rr][c] = W1[(ti * 32 + rr) * H + tj * 32 + c];
        __syncthreads();
#pragma unroll
        for (int rr = r; rr < 32; rr += 8)
            W1t[(tj * 32 + rr) * H + ti * 32 + c] = f2bf(tile[c][rr]);
    } else if (b < 192) {
        // Wpt[j][i] = bf16(Wp[i][j]); Wp is [512][256]
        __shared__ float tile[32][33];
        const int b2 = b - 64;
        const int ti = b2 >> 3, tj = b2 & 7;     // ti over i (16), tj over j (8)
        const int r  = threadIdx.x >> 5, c = threadIdx.x & 31;
#pragma unroll
        for (int rr = r; rr < 32; rr += 8)
            tile[rr][c] = Wp[(ti * 32 + rr) * H + tj * 32 + c];
        __syncthreads();
#pragma unroll
        for (int rr = r; rr < 32; rr += 8)
            Wpt[(tj * 32 + rr) * (2 * H) + ti * 32 + c] = f2bf(tile[c][rr]);
    } else if (b < 256) {
        // W2b = bf16(W2), same layout
        const int e4 = (b - 192) * 1024 + threadIdx.x * 4;
        float4 v = *(const float4*)&W2[e4];
        ushort4 o;
        o.x = f2bf(v.x); o.y = f2bf(v.y); o.z = f2bf(v.z); o.w = f2bf(v.w);
        *(ushort4*)&W2b[e4] = o;
    } else {
        int i = (b - 256) * 256 + threadIdx.x;
        if (i < N) {
            float x = pos[3 * i], y = pos[3 * i + 1], z = pos[3 * i + 2];
            float4 P = make_float4(x, y, z, 0.f);
            int c = cell_of(x, y, z);
            int slot = atomicAdd(&cellcnt[c], 1);
            if (slot < SLOTS) {
                pos4s[c * SLOTS + slot] = P;
                origidx[c * SLOTS + slot] = i;
            } else {
                int o = atomicAdd(&cellcnt[4096], 1);   // overflow count
                if (o < OCAP) { ovfpos[o] = P; ovfidx[o] = i; }
            }
        }
    }
}

// ---- fused: cell-count tau -> phase1 exact tau* -> phase2 -> top-32 ->
//      embed -> MFMA GEMM1 -> gelu/mean -> W2 matvec -> featsB (bf16) ----
__global__ __launch_bounds__(TPB, 8)
void fused_knn_mlp(const float* __restrict__ pos,
                   const float4* __restrict__ pos4s,
                   const int* __restrict__ origidx,
                   const int* __restrict__ cellcnt,
                   const int* __restrict__ ovfidx, const float4* __restrict__ ovfpos,
                   const int* __restrict__ supidx,
                   const ushort* __restrict__ W1t, const float* __restrict__ b1,
                   const ushort* __restrict__ W2b, const float* __restrict__ b2,
                   ushort* __restrict__ featsB)
{
    __shared__ __align__(16) char pool[16384];
    float* amaxd = (float*)pool;
    int*   acnt  = (int*)(pool + 512);
    int*   ccell = (int*)(pool + 1024);
    int*   ccnt  = (int*)(pool + 2048);
    float* cmnd  = (float*)(pool + 3072);
    int*   cpre  = (int*)(pool + 4096);
    float* d2buf = (float*)(pool + 5120);
    int*   obuf  = (int*)(pool + 7168);
    float* pxb   = (float*)(pool + 9216);
    float* pyb   = (float*)(pool + 11264);
    float* pzb   = (float*)(pool + 13312);
    ushort* msg  = (ushort*)pool;
    float*  p2   = (float*)pool;

    __shared__ float rf[KNB][5];
    __shared__ int   selo[KNB];
    __shared__ float hb[H];
    __shared__ int   wsum[4];
    __shared__ float tau2_sh, tau32_sh;
    __shared__ int   cnt_sh, ncl;

    const int s    = blockIdx.x;
    const int t    = threadIdx.x;
    const int lane = t & 63;
    const int w    = t >> 6;       // wave 0..7

    const int sidx = supidx[s];
    const float sx = pos[3 * sidx], sy = pos[3 * sidx + 1], sz = pos[3 * sidx + 2];

    constexpr float L2_10000 = 13.287712379549449f;

    if (t == 0) { ncl = 0; tau2_sh = 301.f; }

    // ---- stage A: issue cellcnt window loads FIRST (latency hidden by supE) ----
    const int scx = min(GC - 1, max(0, (int)(sx * HINV)));
    const int scy = min(GC - 1, max(0, (int)(sy * HINV)));
    const int scz = min(GC - 1, max(0, (int)(sz * HINV)));
    const int ax0 = max(0, scx - 2), ax1 = min(GC - 1, scx + 2);
    const int ay0 = max(0, scy - 2), ay1 = min(GC - 1, scy + 2);
    const int az0 = max(0, scz - 2), az1 = min(GC - 1, scz + 2);
    const int anx = ax1 - ax0 + 1, any_ = ay1 - ay0 + 1, anz = az1 - az0 + 1;
    const int an  = anx * any_ * anz;    // <= 125
    if (t < an) {
        int ci = t;
        int X = ax0 + ci % anx, rem = ci / anx;
        int Y = ay0 + rem % any_, Z = az0 + rem / any_;
        int cell = (Z * GC + Y) * GC + X;
        acnt[ci] = min(cellcnt[cell], SLOTS);
        float lx = X * HCEL, ly = Y * HCEL, lz = Z * HCEL;
        float mx = fmaxf(fabsf(sx - lx), fabsf(lx + HCEL - sx));
        float my = fmaxf(fabsf(sy - ly), fabsf(ly + HCEL - sy));
        float mz = fmaxf(fabsf(sz - lz), fabsf(lz + HCEL - sz));
        amaxd[ci] = mx * mx + my * my + mz * mz;
    }

    // supE embed -> featsB[s][0..255] (bf16), overlapping the loads above
    if (t < 256) {
        float se = 0.f;
        if (t < 252) {
            int c  = t / 84;
            int rr = t - c * 84;
            int f  = (rr < 42) ? rr : rr - 42;
            float coord = (c == 0) ? sx : ((c == 1) ? sy : sz);
            float ang = coord * exp2f(-(float)f * (L2_10000 / 42.f));
            se = (rr < 42) ? __sinf(ang) : __cosf(ang);
        }
        featsB[s * (2 * H) + t] = f2bf(se);
    }
    __syncthreads();
    if (t < an) {
        int ci = t;
        float myv = amaxd[ci];
        int Sc = 0;
        for (int j = 0; j < an; j++) {
            bool less = (amaxd[j] < myv) || (amaxd[j] == myv && j < ci);
            Sc += less ? acnt[j] : 0;
        }
        if (Sc < KNB && KNB <= Sc + acnt[ci]) tau2_sh = myv;
    }
    __syncthreads();
    const float tau2 = tau2_sh;
    const float R2 = tau2 + 1e-3f;
    const float R  = sqrtf(R2);
    if (t == 0) tau32_sh = R2;   // fallback if phase1 < 32

    // ---- stage B: build ball-cell list (cell, cnt|p1flag, mind2) ----
    const int bx0 = max(0, (int)floorf((sx - R) * HINV));
    const int bx1 = min(GC - 1, (int)floorf((sx + R) * HINV));
    const int by0 = max(0, (int)floorf((sy - R) * HINV));
    const int by1 = min(GC - 1, (int)floorf((sy + R) * HINV));
    const int bz0 = max(0, (int)floorf((sz - R) * HINV));
    const int bz1 = min(GC - 1, (int)floorf((sz + R) * HINV));
    const bool inwin = (bx0 >= ax0 && bx1 <= ax1 && by0 >= ay0 && by1 <= ay1 &&
                        bz0 >= az0 && bz1 <= az1);
    if (inwin) {
        if (t < an) {
            int ci = t;
            int cn = acnt[ci];
            if (cn > 0) {
                int X = ax0 + ci % anx, rem = ci / anx;
                int Y = ay0 + rem % any_, Z = az0 + rem / any_;
                float lx = X * HCEL, ly = Y * HCEL, lz = Z * HCEL;
                float ddx = fmaxf(fmaxf(lx - sx, sx - (lx + HCEL)), 0.f);
                float ddy = fmaxf(fmaxf(ly - sy, sy - (ly + HCEL)), 0.f);
                float ddz = fmaxf(fmaxf(lz - sz, sz - (lz + HCEL)), 0.f);
                float mnd = ddx * ddx + ddy * ddy + ddz * ddz;
                if (mnd <= R2) {
                    int p1 = (amaxd[ci] <= tau2) ? 1 : 0;
                    int cell = (Z * GC + Y) * GC + X;
                    int sl = atomicAdd(&ncl, 1);
                    if (sl < 256) { ccell[sl] = cell; ccnt[sl] = cn | (p1 << 8); cmnd[sl] = mnd; }
                }
            }
        }
    } else {
        const int nbx = bx1 - bx0 + 1, nby = by1 - by0 + 1, nbz = bz1 - bz0 + 1;
        const int ncb = nbx * nby * nbz;
        for (int ci = t; ci < ncb; ci += TPB) {
            int X = bx0 + ci % nbx, rem = ci / nbx;
            int Y = by0 + rem % nby, Z = bz0 + rem / nby;
            float lx = X * HCEL, ly = Y * HCEL, lz = Z * HCEL;
            float ddx = fmaxf(fmaxf(lx - sx, sx - (lx + HCEL)), 0.f);
            float ddy = fmaxf(fmaxf(ly - sy, sy - (ly + HCEL)), 0.f);
            float ddz = fmaxf(fmaxf(lz - sz, sz - (lz + HCEL)), 0.f);
            float mnd = ddx * ddx + ddy * ddy + ddz * ddz;
            if (mnd > R2) continue;
            int cell = (Z * GC + Y) * GC + X;
            int cn = min(cellcnt[cell], SLOTS);
            if (cn == 0) continue;
            float mx = fmaxf(fabsf(sx - lx), fabsf(lx + HCEL - sx));
            float my = fmaxf(fabsf(sy - ly), fabsf(ly + HCEL - sy));
            float mz = fmaxf(fabsf(sz - lz), fabsf(lz + HCEL - sz));
            float amx = mx * mx + my * my + mz * mz;
            int p1 = (amx <= tau2) ? 1 : 0;
            int sl = atomicAdd(&ncl, 1);
            if (sl < 256) { ccell[sl] = cell; ccnt[sl] = cn | (p1 << 8); cmnd[sl] = mnd; }
        }
    }
    __syncthreads();
    const int nclc = min(ncl, 256);

    auto build_prefix = [&](int phase, float tlim) -> int {
        int v = 0;
        if (t < 256) {
            if (t < nclc) {
                int cc = ccnt[t];
                int cn = cc & 0xff;
                int p1 = cc >> 8;
                v = (phase == 1) ? (p1 ? cn : 0)
                                 : ((!p1 && cmnd[t] <= tlim) ? cn : 0);
            }
#pragma unroll
            for (int off = 1; off < 64; off <<= 1) {
                int x = __shfl_up(v, off);
                if (lane >= off) v += x;
            }
            if (lane == 63) wsum[w] = v;
        }
        __syncthreads();
        if (t < 256) {
            int add = 0;
#pragma unroll
            for (int j = 0; j < 4; j++) if (j < w) add += wsum[j];
            cpre[t] = v + add;
        }
        __syncthreads();
        return cpre[255];
    };
    auto bsearch = [&](int j) -> int {
        int lo = 0;
#pragma unroll
        for (int st = 128; st; st >>= 1) {
            int nlo = lo + st;
            if (nlo <= 256 && cpre[nlo - 1] <= j) lo = nlo;
        }
        return lo;
    };

    // ---- phase 1: gather ALL points of P1 cells (dense, no atomics) ----
    const int tot1 = build_prefix(1, 0.f);
    const int M1 = min(tot1, CAP);
    if (t < M1) {
        int j = t;
        int lo = bsearch(j);
        int off = j - (lo ? cpre[lo - 1] : 0);
        int u = ccell[lo] * SLOTS + off;
        float4 P = pos4s[u];
        float dx = sx - P.x, dy = sy - P.y, dz = sz - P.z;
        d2buf[j] = dx * dx + dy * dy + dz * dz;
        obuf[j]  = origidx[u];
        pxb[j] = P.x; pyb[j] = P.y; pzb[j] = P.z;
    }
    const int Mp1 = (M1 + 3) & ~3;
    if (M1 + t < Mp1) { d2buf[M1 + t] = INFINITY; obuf[M1 + t] = 0x7fffffff; }
    if (t == 0) cnt_sh = M1;
    __syncthreads();

    if (t < M1) {
        int u = t;
        float myv = d2buf[u];
        int   myo = obuf[u];
        int rank = 0;
        for (int v2 = 0; v2 < Mp1; v2 += 4) {
            float4 dv = *(const float4*)&d2buf[v2];
            int4   iv = *(const int4*)&obuf[v2];
            rank += (dv.x < myv) || (dv.x == myv && iv.x < myo);
            rank += (dv.y < myv) || (dv.y == myv && iv.y < myo);
            rank += (dv.z < myv) || (dv.z == myv && iv.z < myo);
            rank += (dv.w < myv) || (dv.w == myv && iv.w < myo);
        }
        if (rank == KNB - 1) tau32_sh = myv;
    }
    __syncthreads();
    const float tau32 = tau32_sh;

    // ---- phase 2: cells with mind2 <= tau*, filter d2 <= tau* ----
    const int tot2 = build_prefix(2, tau32);
    for (int j0 = 0; j0 < tot2; j0 += TPB) {
        int j = j0 + t;
        bool pass = false; float pd2 = 0.f; int po = 0; float qx = 0, qy = 0, qz = 0;
        if (j < tot2) {
            int lo = bsearch(j);
            int off = j - (lo ? cpre[lo - 1] : 0);
            int u = ccell[lo] * SLOTS + off;
            float4 P = pos4s[u];
            float dx = sx - P.x, dy = sy - P.y, dz = sz - P.z;
            pd2 = dx * dx + dy * dy + dz * dz;
            if (pd2 <= tau32) { pass = true; po = origidx[u]; qx = P.x; qy = P.y; qz = P.z; }
        }
        unsigned long long m = __ballot(pass);
        if (m) {
            int ldr = __ffsll(m) - 1;
            int base = 0;
            if (lane == ldr) base = atomicAdd(&cnt_sh, __popcll(m));
            base = __shfl(base, ldr);
            if (pass) {
                int slp = base + __popcll(m & ((1ull << lane) - 1ull));
                if (slp < CAP) {
                    d2buf[slp] = pd2; obuf[slp] = po;
                    pxb[slp] = qx; pyb[slp] = qy; pzb[slp] = qz;
                }
            }
        }
    }
    {
        int no = min(cellcnt[4096], OCAP);
        for (int j = t; j < no; j += TPB) {
            float4 P = ovfpos[j];
            float dx = sx - P.x, dy = sy - P.y, dz = sz - P.z;
            float pd2 = dx * dx + dy * dy + dz * dz;
            if (pd2 <= tau32) {
                int slp = atomicAdd(&cnt_sh, 1);
                if (slp < CAP) {
                    d2buf[slp] = pd2; obuf[slp] = ovfidx[j];
                    pxb[slp] = P.x; pyb[slp] = P.y; pzb[slp] = P.z;
                }
            }
        }
    }
    __syncthreads();
    const int M = min(cnt_sh, CAP);
    const int Mpad = (M + 3) & ~3;
    if (M + t < Mpad) { d2buf[M + t] = INFINITY; obuf[M + t] = 0x7fffffff; }
    __syncthreads();

    if (t < M) {
        int u = t;
        float myv = d2buf[u];
        int   myo = obuf[u];
        int rank = 0;
        for (int v2 = 0; v2 < Mpad; v2 += 4) {
            float4 dv = *(const float4*)&d2buf[v2];
            int4   iv = *(const int4*)&obuf[v2];
            rank += (dv.x < myv) || (dv.x == myv && iv.x < myo);
            rank += (dv.y < myv) || (dv.y == myv && iv.y < myo);
            rank += (dv.z < myv) || (dv.z == myv && iv.z < myo);
            rank += (dv.w < myv) || (dv.w == myv && iv.w < myo);
        }
        if (rank < KNB) selo[rank] = u;
    }
    __syncthreads();
    if (t < KNB) {
        int u = selo[t];
        float rx = sx - pxb[u], ry = sy - pyb[u], rz = sz - pzb[u];
        float dd = sqrtf(d2buf[u]);
        rf[t][0] = rx; rf[t][1] = ry; rf[t][2] = rz; rf[t][3] = dd;
    }
    __syncthreads();   // select stage dead; msg takes pool

    // ---- sincos embed -> msg[k][i] bf16, row-XOR swizzle ----
#pragma unroll
    for (int n = 0; n < 8; n++) {
        int item = t + n * TPB;
        int f = item & 31;
        int c = (item >> 5) & 3;
        int k = item >> 7;
        float ang = rf[k][c] * exp2f(-(float)f * (L2_10000 / 32.f));
        int swz = (k & 7) << 3;
        msg[((k << 8) | (c * 64 + f))      ^ swz] = f2bf(__sinf(ang));
        msg[((k << 8) | (c * 64 + 32 + f)) ^ swz] = f2bf(__cosf(ang));
    }
    __syncthreads();

    // ---- MFMA GEMM1: wave w owns j-rows [32w, 32w+32) ----
    {
        const int lr = lane & 15;
        const int lg = lane >> 4;
        f32x4 acc00 = {0,0,0,0}, acc01 = {0,0,0,0};
        f32x4 acc10 = {0,0,0,0}, acc11 = {0,0,0,0};
#pragma unroll
        for (int kk = 0; kk < 8; kk++) {
            const int i0 = kk * 32 + lg * 8;
            bf16x8 a0 = *(const bf16x8*)(W1t + ((32 * w      + lr) << 8) + i0);
            bf16x8 a1 = *(const bf16x8*)(W1t + ((32 * w + 16 + lr) << 8) + i0);
            const int swz = (lr & 7) << 3;
            bf16x8 b0  = *(const bf16x8*)(msg + ((( lr       << 8) | i0) ^ swz));
            bf16x8 b1v = *(const bf16x8*)(msg + ((((lr + 16) << 8) | i0) ^ swz));
            acc00 = __builtin_amdgcn_mfma_f32_16x16x32_bf16(a0, b0,  acc00, 0, 0, 0);
            acc01 = __builtin_amdgcn_mfma_f32_16x16x32_bf16(a0, b1v, acc01, 0, 0, 0);
            acc10 = __builtin_amdgcn_mfma_f32_16x16x32_bf16(a1, b0,  acc10, 0, 0, 0);
            acc11 = __builtin_amdgcn_mfma_f32_16x16x32_bf16(a1, b1v, acc11, 0, 0, 0);
        }
        float part[8];
#pragma unroll
        for (int mm = 0; mm < 2; mm++)
#pragma unroll
            for (int r = 0; r < 4; r++) {
                int j = 32 * w + 16 * mm + 4 * lg + r;
                float bj = b1[j];
                float h0 = (mm == 0 ? acc00[r] : acc10[r]) + bj;
                float h1 = (mm == 0 ? acc01[r] : acc11[r]) + bj;
                part[mm * 4 + r] = gelu_fast(h0) + gelu_fast(h1);
            }
#pragma unroll
        for (int off = 1; off < 16; off <<= 1)
#pragma unroll
            for (int u = 0; u < 8; u++)
                part[u] += __shfl_xor(part[u], off);
        if (lr == 0) {
#pragma unroll
            for (int u = 0; u < 8; u++) {
                int mm = u >> 2, r = u & 3;
                hb[32 * w + 16 * mm + 4 * lg + r] = part[u] * (1.0f / 32.0f);
            }
        }
    }
    __syncthreads();   // hb ready; msg dead -> p2

    // ---- W2 matvec (bf16 W2): group w handles i in [32w,32w+32) ----
    {
        const int j4 = lane * 4;
        const int ib = w * 32;
        float4 a = {0.f, 0.f, 0.f, 0.f};
#pragma unroll 4
        for (int i = 0; i < 32; i++) {
            float hv = hb[ib + i];
            ushort4 wv = *(const ushort4*)&W2b[(ib + i) * H + j4];
            a.x = fmaf(hv, bf2f(wv.x), a.x);
            a.y = fmaf(hv, bf2f(wv.y), a.y);
            a.z = fmaf(hv, bf2f(wv.z), a.z);
            a.w = fmaf(hv, bf2f(wv.w), a.w);
        }
        *(float4*)&p2[w * 256 + j4] = a;
    }
    __syncthreads();
    if (t < 256) {
        float agg = b2[t];
#pragma unroll
        for (int g = 0; g < 8; g++) agg += p2[g * 256 + t];
        featsB[s * (2 * H) + H + t] = f2bf(agg);
    }
}

// ---- mfma_out: out[s][j] = featsB[s][:] . Wpt[j][:] + bp[j]  (bf16 MFMA) ----
// grid = S/32 blocks x 512 thr; wave w owns j in [32w, 32w+32); no LDS/barriers
__global__ __launch_bounds__(512)
void mfma_out(const ushort* __restrict__ featsB, const ushort* __restrict__ Wpt,
              const float* __restrict__ bp, float* __restrict__ out)
{
    const int bm   = blockIdx.x;
    const int t    = threadIdx.x;
    const int lane = t & 63;
    const int w    = t >> 6;
    const int lr   = lane & 15;
    const int lg   = lane >> 4;

    f32x4 acc[2][2];
#pragma unroll
    for (int mt = 0; mt < 2; mt++)
#pragma unroll
        for (int nt = 0; nt < 2; nt++) acc[mt][nt] = (f32x4){0, 0, 0, 0};

#pragma unroll
    for (int kk = 0; kk < 16; kk++) {
        const int i0 = kk * 32 + lg * 8;
        bf16x8 a0 = *(const bf16x8*)(featsB + (32 * bm      + lr) * 512 + i0);
        bf16x8 a1 = *(const bf16x8*)(featsB + (32 * bm + 16 + lr) * 512 + i0);
        bf16x8 b0 = *(const bf16x8*)(Wpt + (32 * w      + lr) * 512 + i0);
        bf16x8 b1 = *(const bf16x8*)(Wpt + (32 * w + 16 + lr) * 512 + i0);
        acc[0][0] = __builtin_amdgcn_mfma_f32_16x16x32_bf16(a0, b0, acc[0][0], 0, 0, 0);
        acc[0][1] = __builtin_amdgcn_mfma_f32_16x16x32_bf16(a0, b1, acc[0][1], 0, 0, 0);
        acc[1][0] = __builtin_amdgcn_mfma_f32_16x16x32_bf16(a1, b0, acc[1][0], 0, 0, 0);
        acc[1][1] = __builtin_amdgcn_mfma_f32_16x16x32_bf16(a1, b1, acc[1][1], 0, 0, 0);
    }
#pragma unroll
    for (int mt = 0; mt < 2; mt++)
#pragma unroll
        for (int nt = 0; nt < 2; nt++)
#pragma unroll
            for (int r = 0; r < 4; r++) {
                int srow = 32 * bm + 16 * mt + 4 * lg + r;
                int j    = 32 * w  + 16 * nt + lr;
                out[srow * H + j] = acc[mt][nt][r] + bp[j];
            }
}

extern "C" void kernel_launch(void* const* d_in, const int* in_sizes, int n_in,
                              void* d_out, int out_size, void* d_ws, size_t ws_size,
                              hipStream_t stream) {
    const float* pos = (const float*)d_in[0];
    const int*   sup = (const int*)d_in[1];
    const float* W1  = (const float*)d_in[2];
    const float* b1  = (const float*)d_in[3];
    const float* W2  = (const float*)d_in[4];
    const float* b2  = (const float*)d_in[5];
    const float* Wp  = (const float*)d_in[6];
    const float* bp  = (const float*)d_in[7];

    const int N = in_sizes[0] / 3;
    const int S = in_sizes[1];
    float* out = (float*)d_out;

    char* ws = (char*)d_ws;
    ushort* W1t     = (ushort*)ws;                      // 128 KB
    ushort* Wpt     = (ushort*)(ws + (128 << 10));      // 256 KB (bf16 [256][512])
    ushort* W2b     = (ushort*)(ws + (384 << 10));      // 128 KB
    float4* pos4s   = (float4*)(ws + (512 << 10));      // 2 MB
    int*    origidx = (int*)(ws + (2560 << 10));        // 512 KB
    int*    cellcnt = (int*)(ws + (3072 << 10));        // 4097 ints
    int*    ovfidx  = (int*)(ws + (3092 << 10));        // 1 KB
    float4* ovfpos  = (float4*)(ws + (3096 << 10));     // 4 KB
    ushort* featsB  = (ushort*)(ws + (3104 << 10));     // 1 MB (bf16 [S][512])

    hipMemsetAsync(cellcnt, 0, 4097 * sizeof(int), stream);
    prep<<<256 + (N + 255) / 256, 256, 0, stream>>>(W1, Wp, W2, pos, N,
                                                    W1t, Wpt, W2b, pos4s,
                                                    origidx, cellcnt, ovfidx, ovfpos);
    fused_knn_mlp<<<S, TPB, 0, stream>>>(pos, pos4s, origidx, cellcnt,
                                         ovfidx, ovfpos, sup,
                                         W1t, b1, W2b, b2, featsB);
    mfma_out<<<S / 32, 512, 0, stream>>>(featsB, Wpt, bp, out);
}

// Round 17
// 77.232 us; speedup vs baseline: 1.9194x; 1.0479x over previous
//
#include <hip/hip_runtime.h>
#include <hip/hip_bf16.h>
#include <math.h>

typedef short bf16x8 __attribute__((ext_vector_type(8)));
typedef float f32x4  __attribute__((ext_vector_type(4)));

constexpr int   H     = 256;
constexpr int   KNB   = 32;
constexpr int   TPB   = 512;     // 8 waves/block
constexpr int   GC    = 16;      // bin-grid cells per dim
constexpr float HINV  = 1.6f;    // GC / 10.0
constexpr float HCEL  = 0.625f;  // 10.0 / GC
constexpr int   SLOTS = 32;      // slots per cell (avg fill ~12.2; overflow spills)
constexpr int   OCAP  = 256;     // overflow list capacity
constexpr int   CAP   = 512;     // candidate buffer

__device__ __forceinline__ ushort f2bf(float x) {
    unsigned u = __float_as_uint(x);
    u += 0x7FFF + ((u >> 16) & 1);
    return (ushort)(u >> 16);
}

__device__ __forceinline__ float gelu_fast(float x) {
    float u = 0.7978845608028654f * (x + 0.044715f * x * x * x);
    float t = exp2f(-2.885390081777927f * u);
    return x / (1.0f + t);
}

__device__ __forceinline__ int cell_of(float x, float y, float z) {
    int cx = min(GC - 1, max(0, (int)(x * HINV)));
    int cy = min(GC - 1, max(0, (int)(y * HINV)));
    int cz = min(GC - 1, max(0, (int)(z * HINV)));
    return (cz * GC + cy) * GC + cx;
}

// ---- prep: W1t (b<64), Wpt (64..191), W2t (192..255), vector scatter (256..) ----
__global__ __launch_bounds__(256)
void prep(const float* __restrict__ W1, const float* __restrict__ Wp,
          const float* __restrict__ W2, const float* __restrict__ pos, int N,
          ushort* __restrict__ W1t, ushort* __restrict__ Wpt,
          ushort* __restrict__ W2t, float4* __restrict__ pos4s,
          int* __restrict__ origidx, int* __restrict__ cellcnt,
          int* __restrict__ ovfidx, float4* __restrict__ ovfpos) {
    const int b = blockIdx.x;
    if (b < 64) {
        __shared__ float tile[32][33];
        const int ti = b >> 3, tj = b & 7;
        const int r  = threadIdx.x >> 5, c = threadIdx.x & 31;
#pragma unroll
        for (int rr = r; rr < 32; rr += 8)
            tile[rr][c] = W1[(ti * 32 + rr) * H + tj * 32 + c];
        __syncthreads();
#pragma unroll
        for (int rr = r; rr < 32; rr += 8)
            W1t[(tj * 32 + rr) * H + ti * 32 + c] = f2bf(tile[c][rr]);
    } else if (b < 192) {
        // Wpt[j][i] = bf16(Wp[i][j]); Wp is [512][256]
        __shared__ float tile[32][33];
        const int b2 = b - 64;
        const int ti = b2 >> 3, tj = b2 & 7;
        const int r  = threadIdx.x >> 5, c = threadIdx.x & 31;
#pragma unroll
        for (int rr = r; rr < 32; rr += 8)
            tile[rr][c] = Wp[(ti * 32 + rr) * H + tj * 32 + c];
        __syncthreads();
#pragma unroll
        for (int rr = r; rr < 32; rr += 8)
            Wpt[(tj * 32 + rr) * (2 * H) + ti * 32 + c] = f2bf(tile[c][rr]);
    } else if (b < 256) {
        // W2t[j][i] = bf16(W2[i][j]); W2 is [256][256]
        __shared__ float tile[32][33];
        const int b2 = b - 192;
        const int ti = b2 >> 3, tj = b2 & 7;
        const int r  = threadIdx.x >> 5, c = threadIdx.x & 31;
#pragma unroll
        for (int rr = r; rr < 32; rr += 8)
            tile[rr][c] = W2[(ti * 32 + rr) * H + tj * 32 + c];
        __syncthreads();
#pragma unroll
        for (int rr = r; rr < 32; rr += 8)
            W2t[(tj * 32 + rr) * H + ti * 32 + c] = f2bf(tile[c][rr]);
    } else {
        // slotted scatter, vectorized: block handles 1024 points
        const int sb = b - 256;
        const int base = sb * 1024;
        const int t = threadIdx.x;
        auto scat = [&](float x, float y, float z, int i) {
            float4 P = make_float4(x, y, z, 0.f);
            int c = cell_of(x, y, z);
            int slot = atomicAdd(&cellcnt[c], 1);
            if (slot < SLOTS) {
                pos4s[c * SLOTS + slot] = P;
                origidx[c * SLOTS + slot] = i;
            } else {
                int o = atomicAdd(&cellcnt[4096], 1);
                if (o < OCAP) { ovfpos[o] = P; ovfidx[o] = i; }
            }
        };
        if (base + 1024 <= N) {
            const float4* p4 = (const float4*)(pos + (size_t)base * 3);
            float4 f0 = p4[3 * t + 0];
            float4 f1 = p4[3 * t + 1];
            float4 f2 = p4[3 * t + 2];
            const int ib = base + 4 * t;
            scat(f0.x, f0.y, f0.z, ib + 0);
            scat(f0.w, f1.x, f1.y, ib + 1);
            scat(f1.z, f1.w, f2.x, ib + 2);
            scat(f2.y, f2.z, f2.w, ib + 3);
        } else {
            for (int i = base + t; i < N; i += 256)
                scat(pos[3 * i], pos[3 * i + 1], pos[3 * i + 2], i);
        }
    }
}

// ---- fused: select (cell-tau -> phase1 tau* -> phase2 -> top-32) ->
//      embed -> MFMA GEMM1 -> gelu/mean -> hbB (bf16); supE -> supEB ----
__global__ __launch_bounds__(TPB, 8)
void fused_knn_mlp(const float* __restrict__ pos,
                   const float4* __restrict__ pos4s,
                   const int* __restrict__ origidx,
                   const int* __restrict__ cellcnt,
                   const int* __restrict__ ovfidx, const float4* __restrict__ ovfpos,
                   const int* __restrict__ supidx,
                   const ushort* __restrict__ W1t, const float* __restrict__ b1,
                   ushort* __restrict__ supEB, ushort* __restrict__ hbB)
{
    __shared__ __align__(16) char pool[16384];
    float* amaxd = (float*)pool;
    int*   acnt  = (int*)(pool + 512);
    int*   ccell = (int*)(pool + 1024);
    int*   ccnt  = (int*)(pool + 2048);
    float* cmnd  = (float*)(pool + 3072);
    int*   cpre  = (int*)(pool + 4096);
    float* d2buf = (float*)(pool + 5120);
    int*   obuf  = (int*)(pool + 7168);
    float* pxb   = (float*)(pool + 9216);
    float* pyb   = (float*)(pool + 11264);
    float* pzb   = (float*)(pool + 13312);
    ushort* msg  = (ushort*)pool;

    __shared__ float rf[KNB][5];
    __shared__ int   selo[KNB];
    __shared__ int   wsum[4];
    __shared__ float tau2_sh, tau32_sh;
    __shared__ int   cnt_sh, ncl;

    const int s    = blockIdx.x;
    const int t    = threadIdx.x;
    const int lane = t & 63;
    const int w    = t >> 6;       // wave 0..7

    const int sidx = supidx[s];
    const float sx = pos[3 * sidx], sy = pos[3 * sidx + 1], sz = pos[3 * sidx + 2];

    constexpr float L2_10000 = 13.287712379549449f;

    if (t == 0) { ncl = 0; tau2_sh = 301.f; }

    // ---- stage A: issue cellcnt window loads FIRST (latency hidden by supE) ----
    const int scx = min(GC - 1, max(0, (int)(sx * HINV)));
    const int scy = min(GC - 1, max(0, (int)(sy * HINV)));
    const int scz = min(GC - 1, max(0, (int)(sz * HINV)));
    const int ax0 = max(0, scx - 2), ax1 = min(GC - 1, scx + 2);
    const int ay0 = max(0, scy - 2), ay1 = min(GC - 1, scy + 2);
    const int az0 = max(0, scz - 2), az1 = min(GC - 1, scz + 2);
    const int anx = ax1 - ax0 + 1, any_ = ay1 - ay0 + 1, anz = az1 - az0 + 1;
    const int an  = anx * any_ * anz;    // <= 125
    if (t < an) {
        int ci = t;
        int X = ax0 + ci % anx, rem = ci / anx;
        int Y = ay0 + rem % any_, Z = az0 + rem / any_;
        int cell = (Z * GC + Y) * GC + X;
        acnt[ci] = min(cellcnt[cell], SLOTS);
        float lx = X * HCEL, ly = Y * HCEL, lz = Z * HCEL;
        float mx = fmaxf(fabsf(sx - lx), fabsf(lx + HCEL - sx));
        float my = fmaxf(fabsf(sy - ly), fabsf(ly + HCEL - sy));
        float mz = fmaxf(fabsf(sz - lz), fabsf(lz + HCEL - sz));
        amaxd[ci] = mx * mx + my * my + mz * mz;
    }

    // supE embed -> supEB[s][0..255] (bf16), overlapping the loads above
    if (t < 256) {
        float se = 0.f;
        if (t < 252) {
            int c  = t / 84;
            int rr = t - c * 84;
            int f  = (rr < 42) ? rr : rr - 42;
            float coord = (c == 0) ? sx : ((c == 1) ? sy : sz);
            float ang = coord * exp2f(-(float)f * (L2_10000 / 42.f));
            se = (rr < 42) ? __sinf(ang) : __cosf(ang);
        }
        supEB[s * H + t] = f2bf(se);
    }
    __syncthreads();
    if (t < an) {
        int ci = t;
        float myv = amaxd[ci];
        int Sc = 0;
        for (int j = 0; j < an; j++) {
            bool less = (amaxd[j] < myv) || (amaxd[j] == myv && j < ci);
            Sc += less ? acnt[j] : 0;
        }
        if (Sc < KNB && KNB <= Sc + acnt[ci]) tau2_sh = myv;
    }
    __syncthreads();
    const float tau2 = tau2_sh;
    const float R2 = tau2 + 1e-3f;
    const float R  = sqrtf(R2);
    if (t == 0) tau32_sh = R2;   // fallback if phase1 < 32

    // ---- stage B: build ball-cell list (cell, cnt|p1flag, mind2) ----
    const int bx0 = max(0, (int)floorf((sx - R) * HINV));
    const int bx1 = min(GC - 1, (int)floorf((sx + R) * HINV));
    const int by0 = max(0, (int)floorf((sy - R) * HINV));
    const int by1 = min(GC - 1, (int)floorf((sy + R) * HINV));
    const int bz0 = max(0, (int)floorf((sz - R) * HINV));
    const int bz1 = min(GC - 1, (int)floorf((sz + R) * HINV));
    const bool inwin = (bx0 >= ax0 && bx1 <= ax1 && by0 >= ay0 && by1 <= ay1 &&
                        bz0 >= az0 && bz1 <= az1);
    if (inwin) {
        if (t < an) {
            int ci = t;
            int cn = acnt[ci];
            if (cn > 0) {
                int X = ax0 + ci % anx, rem = ci / anx;
                int Y = ay0 + rem % any_, Z = az0 + rem / any_;
                float lx = X * HCEL, ly = Y * HCEL, lz = Z * HCEL;
                float ddx = fmaxf(fmaxf(lx - sx, sx - (lx + HCEL)), 0.f);
                float ddy = fmaxf(fmaxf(ly - sy, sy - (ly + HCEL)), 0.f);
                float ddz = fmaxf(fmaxf(lz - sz, sz - (lz + HCEL)), 0.f);
                float mnd = ddx * ddx + ddy * ddy + ddz * ddz;
                if (mnd <= R2) {
                    int p1 = (amaxd[ci] <= tau2) ? 1 : 0;
                    int cell = (Z * GC + Y) * GC + X;
                    int sl = atomicAdd(&ncl, 1);
                    if (sl < 256) { ccell[sl] = cell; ccnt[sl] = cn | (p1 << 8); cmnd[sl] = mnd; }
                }
            }
        }
    } else {
        const int nbx = bx1 - bx0 + 1, nby = by1 - by0 + 1, nbz = bz1 - bz0 + 1;
        const int ncb = nbx * nby * nbz;
        for (int ci = t; ci < ncb; ci += TPB) {
            int X = bx0 + ci % nbx, rem = ci / nbx;
            int Y = by0 + rem % nby, Z = bz0 + rem / nby;
            float lx = X * HCEL, ly = Y * HCEL, lz = Z * HCEL;
            float ddx = fmaxf(fmaxf(lx - sx, sx - (lx + HCEL)), 0.f);
            float ddy = fmaxf(fmaxf(ly - sy, sy - (ly + HCEL)), 0.f);
            float ddz = fmaxf(fmaxf(lz - sz, sz - (lz + HCEL)), 0.f);
            float mnd = ddx * ddx + ddy * ddy + ddz * ddz;
            if (mnd > R2) continue;
            int cell = (Z * GC + Y) * GC + X;
            int cn = min(cellcnt[cell], SLOTS);
            if (cn == 0) continue;
            float mx = fmaxf(fabsf(sx - lx), fabsf(lx + HCEL - sx));
            float my = fmaxf(fabsf(sy - ly), fabsf(ly + HCEL - sy));
            float mz = fmaxf(fabsf(sz - lz), fabsf(lz + HCEL - sz));
            float amx = mx * mx + my * my + mz * mz;
            int p1 = (amx <= tau2) ? 1 : 0;
            int sl = atomicAdd(&ncl, 1);
            if (sl < 256) { ccell[sl] = cell; ccnt[sl] = cn | (p1 << 8); cmnd[sl] = mnd; }
        }
    }
    __syncthreads();
    const int nclc = min(ncl, 256);

    auto build_prefix = [&](int phase, float tlim) -> int {
        int v = 0;
        if (t < 256) {
            if (t < nclc) {
                int cc = ccnt[t];
                int cn = cc & 0xff;
                int p1 = cc >> 8;
                v = (phase == 1) ? (p1 ? cn : 0)
                                 : ((!p1 && cmnd[t] <= tlim) ? cn : 0);
            }
#pragma unroll
            for (int off = 1; off < 64; off <<= 1) {
                int x = __shfl_up(v, off);
                if (lane >= off) v += x;
            }
            if (lane == 63) wsum[w] = v;
        }
        __syncthreads();
        if (t < 256) {
            int add = 0;
#pragma unroll
            for (int j = 0; j < 4; j++) if (j < w) add += wsum[j];
            cpre[t] = v + add;
        }
        __syncthreads();
        return cpre[255];
    };
    auto bsearch = [&](int j) -> int {
        int lo = 0;
#pragma unroll
        for (int st = 128; st; st >>= 1) {
            int nlo = lo + st;
            if (nlo <= 256 && cpre[nlo - 1] <= j) lo = nlo;
        }
        return lo;
    };

    // ---- phase 1: gather ALL points of P1 cells (dense, no atomics) ----
    const int tot1 = build_prefix(1, 0.f);
    const int M1 = min(tot1, CAP);
    if (t < M1) {
        int j = t;
        int lo = bsearch(j);
        int off = j - (lo ? cpre[lo - 1] : 0);
        int u = ccell[lo] * SLOTS + off;
        float4 P = pos4s[u];
        float dx = sx - P.x, dy = sy - P.y, dz = sz - P.z;
        d2buf[j] = dx * dx + dy * dy + dz * dz;
        obuf[j]  = origidx[u];
        pxb[j] = P.x; pyb[j] = P.y; pzb[j] = P.z;
    }
    const int Mp1 = (M1 + 3) & ~3;
    if (M1 + t < Mp1) { d2buf[M1 + t] = INFINITY; obuf[M1 + t] = 0x7fffffff; }
    if (t == 0) cnt_sh = M1;
    __syncthreads();

    if (t < M1) {
        int u = t;
        float myv = d2buf[u];
        int   myo = obuf[u];
        int rank = 0;
        for (int v2 = 0; v2 < Mp1; v2 += 4) {
            float4 dv = *(const float4*)&d2buf[v2];
            int4   iv = *(const int4*)&obuf[v2];
            rank += (dv.x < myv) || (dv.x == myv && iv.x < myo);
            rank += (dv.y < myv) || (dv.y == myv && iv.y < myo);
            rank += (dv.z < myv) || (dv.z == myv && iv.z < myo);
            rank += (dv.w < myv) || (dv.w == myv && iv.w < myo);
        }
        if (rank == KNB - 1) tau32_sh = myv;
    }
    __syncthreads();
    const float tau32 = tau32_sh;

    // ---- phase 2: cells with mind2 <= tau*, filter d2 <= tau* ----
    const int tot2 = build_prefix(2, tau32);
    for (int j0 = 0; j0 < tot2; j0 += TPB) {
        int j = j0 + t;
        bool pass = false; float pd2 = 0.f; int po = 0; float qx = 0, qy = 0, qz = 0;
        if (j < tot2) {
            int lo = bsearch(j);
            int off = j - (lo ? cpre[lo - 1] : 0);
            int u = ccell[lo] * SLOTS + off;
            float4 P = pos4s[u];
            float dx = sx - P.x, dy = sy - P.y, dz = sz - P.z;
            pd2 = dx * dx + dy * dy + dz * dz;
            if (pd2 <= tau32) { pass = true; po = origidx[u]; qx = P.x; qy = P.y; qz = P.z; }
        }
        unsigned long long m = __ballot(pass);
        if (m) {
            int ldr = __ffsll(m) - 1;
            int base = 0;
            if (lane == ldr) base = atomicAdd(&cnt_sh, __popcll(m));
            base = __shfl(base, ldr);
            if (pass) {
                int slp = base + __popcll(m & ((1ull << lane) - 1ull));
                if (slp < CAP) {
                    d2buf[slp] = pd2; obuf[slp] = po;
                    pxb[slp] = qx; pyb[slp] = qy; pzb[slp] = qz;
                }
            }
        }
    }
    {
        int no = min(cellcnt[4096], OCAP);
        for (int j = t; j < no; j += TPB) {
            float4 P = ovfpos[j];
            float dx = sx - P.x, dy = sy - P.y, dz = sz - P.z;
            float pd2 = dx * dx + dy * dy + dz * dz;
            if (pd2 <= tau32) {
                int slp = atomicAdd(&cnt_sh, 1);
                if (slp < CAP) {
                    d2buf[slp] = pd2; obuf[slp] = ovfidx[j];
                    pxb[slp] = P.x; pyb[slp] = P.y; pzb[slp] = P.z;
                }
            }
        }
    }
    __syncthreads();
    const int M = min(cnt_sh, CAP);
    const int Mpad = (M + 3) & ~3;
    if (M + t < Mpad) { d2buf[M + t] = INFINITY; obuf[M + t] = 0x7fffffff; }
    __syncthreads();

    if (t < M) {
        int u = t;
        float myv = d2buf[u];
        int   myo = obuf[u];
        int rank = 0;
        for (int v2 = 0; v2 < Mpad; v2 += 4) {
            float4 dv = *(const float4*)&d2buf[v2];
            int4   iv = *(const int4*)&obuf[v2];
            rank += (dv.x < myv) || (dv.x == myv && iv.x < myo);
            rank += (dv.y < myv) || (dv.y == myv && iv.y < myo);
            rank += (dv.z < myv) || (dv.z == myv && iv.z < myo);
            rank += (dv.w < myv) || (dv.w == myv && iv.w < myo);
        }
        if (rank < KNB) selo[rank] = u;
    }
    __syncthreads();
    if (t < KNB) {
        int u = selo[t];
        float rx = sx - pxb[u], ry = sy - pyb[u], rz = sz - pzb[u];
        float dd = sqrtf(d2buf[u]);
        rf[t][0] = rx; rf[t][1] = ry; rf[t][2] = rz; rf[t][3] = dd;
    }
    __syncthreads();   // select stage dead; msg takes pool

    // ---- sincos embed -> msg[k][i] bf16, row-XOR swizzle ----
#pragma unroll
    for (int n = 0; n < 8; n++) {
        int item = t + n * TPB;
        int f = item & 31;
        int c = (item >> 5) & 3;
        int k = item >> 7;
        float ang = rf[k][c] * exp2f(-(float)f * (L2_10000 / 32.f));
        int swz = (k & 7) << 3;
        msg[((k << 8) | (c * 64 + f))      ^ swz] = f2bf(__sinf(ang));
        msg[((k << 8) | (c * 64 + 32 + f)) ^ swz] = f2bf(__cosf(ang));
    }
    __syncthreads();

    // ---- MFMA GEMM1: wave w owns j-rows [32w, 32w+32); epilogue -> hbB bf16 ----
    {
        const int lr = lane & 15;
        const int lg = lane >> 4;
        f32x4 acc00 = {0,0,0,0}, acc01 = {0,0,0,0};
        f32x4 acc10 = {0,0,0,0}, acc11 = {0,0,0,0};
#pragma unroll
        for (int kk = 0; kk < 8; kk++) {
            const int i0 = kk * 32 + lg * 8;
            bf16x8 a0 = *(const bf16x8*)(W1t + ((32 * w      + lr) << 8) + i0);
            bf16x8 a1 = *(const bf16x8*)(W1t + ((32 * w + 16 + lr) << 8) + i0);
            const int swz = (lr & 7) << 3;
            bf16x8 b0  = *(const bf16x8*)(msg + ((( lr       << 8) | i0) ^ swz));
            bf16x8 b1v = *(const bf16x8*)(msg + ((((lr + 16) << 8) | i0) ^ swz));
            acc00 = __builtin_amdgcn_mfma_f32_16x16x32_bf16(a0, b0,  acc00, 0, 0, 0);
            acc01 = __builtin_amdgcn_mfma_f32_16x16x32_bf16(a0, b1v, acc01, 0, 0, 0);
            acc10 = __builtin_amdgcn_mfma_f32_16x16x32_bf16(a1, b0,  acc10, 0, 0, 0);
            acc11 = __builtin_amdgcn_mfma_f32_16x16x32_bf16(a1, b1v, acc11, 0, 0, 0);
        }
        float part[8];
#pragma unroll
        for (int mm = 0; mm < 2; mm++)
#pragma unroll
            for (int r = 0; r < 4; r++) {
                int j = 32 * w + 16 * mm + 4 * lg + r;
                float bj = b1[j];
                float h0 = (mm == 0 ? acc00[r] : acc10[r]) + bj;
                float h1 = (mm == 0 ? acc01[r] : acc11[r]) + bj;
                part[mm * 4 + r] = gelu_fast(h0) + gelu_fast(h1);
            }
#pragma unroll
        for (int off = 1; off < 16; off <<= 1)
#pragma unroll
            for (int u = 0; u < 8; u++)
                part[u] += __shfl_xor(part[u], off);
        if (lr == 0) {
#pragma unroll
            for (int u = 0; u < 8; u++) {
                int mm = u >> 2, r = u & 3;
                hbB[s * H + 32 * w + 16 * mm + 4 * lg + r] = f2bf(part[u] * (1.0f / 32.0f));
            }
        }
    }
}

// ---- mfma_out2: 64 blocks x 512; 16 s-rows each.
//  stage1: agg[j][s] = sum_i W2t[j][i]*hbB[s][i] + b2  -> swizzled LDS bf16
//  stage2: out[s][jo] = sum_io Wpt[jo][io]*feats[s][io] + bp ----
__global__ __launch_bounds__(512)
void mfma_out2(const ushort* __restrict__ hbB, const ushort* __restrict__ supEB,
               const ushort* __restrict__ W2t, const float* __restrict__ b2,
               const ushort* __restrict__ Wpt, const float* __restrict__ bp,
               float* __restrict__ out)
{
    __shared__ ushort agg[16 * 256];   // [s_local][j], row-XOR swizzled
    const int bm   = blockIdx.x;       // 16 supernode rows
    const int t    = threadIdx.x;
    const int lane = t & 63;
    const int w    = t >> 6;
    const int lr   = lane & 15;
    const int lg   = lane >> 4;

    // stage 1
    f32x4 acc1[2] = {{0,0,0,0},{0,0,0,0}};
#pragma unroll
    for (int kk = 0; kk < 8; kk++) {
        const int i0 = kk * 32 + lg * 8;
        bf16x8 bf = *(const bf16x8*)(hbB + (16 * bm + lr) * H + i0);
        bf16x8 a0 = *(const bf16x8*)(W2t + ((32 * w      + lr) << 8) + i0);
        bf16x8 a1 = *(const bf16x8*)(W2t + ((32 * w + 16 + lr) << 8) + i0);
        acc1[0] = __builtin_amdgcn_mfma_f32_16x16x32_bf16(a0, bf, acc1[0], 0, 0, 0);
        acc1[1] = __builtin_amdgcn_mfma_f32_16x16x32_bf16(a1, bf, acc1[1], 0, 0, 0);
    }
#pragma unroll
    for (int mt = 0; mt < 2; mt++)
#pragma unroll
        for (int r = 0; r < 4; r++) {
            int j = 32 * w + 16 * mt + 4 * lg + r;
            int sl = lane & 15;                       // D col = s_local
            float v = acc1[mt][r] + b2[j];
            agg[((sl << 8) | j) ^ ((sl & 7) << 3)] = f2bf(v);
        }
    __syncthreads();

    // stage 2
    f32x4 acc2[2] = {{0,0,0,0},{0,0,0,0}};
#pragma unroll
    for (int kk = 0; kk < 16; kk++) {
        const int io = kk * 32 + lg * 8;
        bf16x8 bf;
        if (kk < 8) {
            bf = *(const bf16x8*)(supEB + (16 * bm + lr) * H + io);
        } else {
            int c = io - 256;
            bf = *(const bf16x8*)(agg + (((lr << 8) | c) ^ ((lr & 7) << 3)));
        }
        bf16x8 a0 = *(const bf16x8*)(Wpt + (32 * w      + lr) * 512 + io);
        bf16x8 a1 = *(const bf16x8*)(Wpt + (32 * w + 16 + lr) * 512 + io);
        acc2[0] = __builtin_amdgcn_mfma_f32_16x16x32_bf16(a0, bf, acc2[0], 0, 0, 0);
        acc2[1] = __builtin_amdgcn_mfma_f32_16x16x32_bf16(a1, bf, acc2[1], 0, 0, 0);
    }
#pragma unroll
    for (int mt = 0; mt < 2; mt++)
#pragma unroll
        for (int r = 0; r < 4; r++) {
            int jo = 32 * w + 16 * mt + 4 * lg + r;
            int srow = 16 * bm + (lane & 15);
            out[srow * H + jo] = acc2[mt][r] + bp[jo];
        }
}

extern "C" void kernel_launch(void* const* d_in, const int* in_sizes, int n_in,
                              void* d_out, int out_size, void* d_ws, size_t ws_size,
                              hipStream_t stream) {
    const float* pos = (const float*)d_in[0];
    const int*   sup = (const int*)d_in[1];
    const float* W1  = (const float*)d_in[2];
    const float* b1  = (const float*)d_in[3];
    const float* W2  = (const float*)d_in[4];
    const float* b2  = (const float*)d_in[5];
    const float* Wp  = (const float*)d_in[6];
    const float* bp  = (const float*)d_in[7];

    const int N = in_sizes[0] / 3;
    const int S = in_sizes[1];
    float* out = (float*)d_out;

    char* ws = (char*)d_ws;
    ushort* W1t     = (ushort*)ws;                      // 128 KB
    ushort* Wpt     = (ushort*)(ws + (128 << 10));      // 256 KB bf16 [256][512]
    ushort* W2t     = (ushort*)(ws + (384 << 10));      // 128 KB bf16 [256][256]
    float4* pos4s   = (float4*)(ws + (512 << 10));      // 2 MB
    int*    origidx = (int*)(ws + (2560 << 10));        // 512 KB
    int*    cellcnt = (int*)(ws + (3072 << 10));        // 4097 ints
    int*    ovfidx  = (int*)(ws + (3092 << 10));        // 1 KB
    float4* ovfpos  = (float4*)(ws + (3096 << 10));     // 4 KB
    ushort* supEB   = (ushort*)(ws + (3104 << 10));     // 512 KB bf16 [S][256]
    ushort* hbB     = (ushort*)(ws + (3616 << 10));     // 512 KB bf16 [S][256]

    hipMemsetAsync(cellcnt, 0, 4097 * sizeof(int), stream);
    const int nscat = (N + 1023) / 1024;
    prep<<<256 + nscat, 256, 0, stream>>>(W1, Wp, W2, pos, N,
                                          W1t, Wpt, W2t, pos4s,
                                          origidx, cellcnt, ovfidx, ovfpos);
    fused_knn_mlp<<<S, TPB, 0, stream>>>(pos, pos4s, origidx, cellcnt,
                                         ovfidx, ovfpos, sup,
                                         W1t, b1, supEB, hbB);
    mfma_out2<<<S / 16, 512, 0, stream>>>(hbB, supEB, W2t, b2, Wpt, bp, out);
}